// Round 7
// baseline (825.654 us; speedup 1.0000x reference)
//
#include <hip/hip_runtime.h>
#include <hip/hip_bf16.h>

typedef short bf16x8 __attribute__((ext_vector_type(8)));
typedef float f32x4 __attribute__((ext_vector_type(4)));
typedef unsigned int u32x4 __attribute__((ext_vector_type(4)));

__device__ __forceinline__ unsigned short f2bf(float f) {
    unsigned int u = __float_as_uint(f);
    unsigned int r = u + 0x7fffu + ((u >> 16) & 1u);
    return (unsigned short)(r >> 16);
}
__device__ __forceinline__ float bf2f(unsigned short b) {
    return __uint_as_float(((unsigned int)b) << 16);
}
__device__ __forceinline__ unsigned int packbf2(float lo, float hi) {
    return ((unsigned int)f2bf(hi) << 16) | (unsigned int)f2bf(lo);
}
__device__ __forceinline__ float bflo(unsigned int v) { return __uint_as_float(v << 16); }
__device__ __forceinline__ float bfhi(unsigned int v) { return __uint_as_float(v & 0xffff0000u); }

#define TSHIFT 14   // src tile = 16384 nodes (4.2 MB of h' rows)

// ---------------- pass 1: per-block histogram over (srctile, dstblock) buckets ----------------
__global__ __launch_bounds__(256) void hist2_k(const int* __restrict__ src, const int* __restrict__ dst,
                                               int* __restrict__ hist, int e, int B, int nbukd,
                                               int nblk, int eb) {
    __shared__ int lh[4096];
    int blk = blockIdx.x, t = threadIdx.x;
    for (int j = t; j < 4096; j += 256) lh[j] = 0;
    __syncthreads();
    int e0 = blk * eb, e1 = min(e, e0 + eb);
    for (int i = e0 + t; i < e1; i += 256) {
        int k = (src[i] >> TSHIFT) * nbukd + (dst[i] >> 8);
        atomicAdd(&lh[k], 1);
    }
    __syncthreads();
    for (int j = t; j < B; j += 256) hist[(size_t)j * nblk + blk] = lh[j];
}

// ---------------- pass 2a: per-bucket exclusive scan over blocks; bucket totals ----------------
__global__ __launch_bounds__(256) void scanA_k(int* __restrict__ hist, int* __restrict__ btot, int nbuk, int nblk) {
    int w = (blockIdx.x * 256 + threadIdx.x) >> 6;
    int lane = threadIdx.x & 63;
    if (w >= nbuk) return;
    size_t base = (size_t)w * nblk;
    int run = 0;
    for (int c = 0; c < nblk; c += 64) {
        int i = c + lane;
        int v = (i < nblk) ? hist[base + i] : 0;
        int orig = v;
        for (int d = 1; d < 64; d <<= 1) { int u = __shfl_up(v, d); if (lane >= d) v += u; }
        if (i < nblk) hist[base + i] = run + v - orig;   // exclusive within bucket
        run += __shfl(v, 63);
    }
    if (lane == 0) btot[w] = run;
}

// ---------------- pass 2b: multi-chunk scan of bucket totals -> bucket bases ----------------
__global__ __launch_bounds__(512) void scanBbig_k(const int* __restrict__ btot, int* __restrict__ bbase, int B) {
    __shared__ int s[512];
    __shared__ int carry;
    int t = threadIdx.x;
    if (t == 0) carry = 0;
    __syncthreads();
    for (int c0 = 0; c0 < B; c0 += 512) {
        int idx = c0 + t;
        int v = (idx < B) ? btot[idx] : 0;
        s[t] = v;
        __syncthreads();
        for (int st = 1; st < 512; st <<= 1) {
            int add = (t >= st) ? s[t - st] : 0;
            __syncthreads();
            s[t] += add;
            __syncthreads();
        }
        if (idx < B) bbase[idx] = carry + s[t] - v;
        __syncthreads();
        if (t == 511) carry += s[511];
        __syncthreads();
    }
    if (t == 0) bbase[B] = carry;
}

// ---------------- pass 3: scatter into (srctile, dstblock) bucket regions ----------------
__global__ __launch_bounds__(256) void scatter2_k(const int* __restrict__ src, const int* __restrict__ dst,
                                                  const int* __restrict__ hist, const int* __restrict__ bbase,
                                                  unsigned int* __restrict__ coarse, int e, int B, int nbukd,
                                                  int nblk, int eb) {
    __shared__ int cur[4096];
    int blk = blockIdx.x, t = threadIdx.x;
    for (int j = t; j < B; j += 256) cur[j] = bbase[j] + hist[(size_t)j * nblk + blk];
    __syncthreads();
    int e0 = blk * eb, e1 = min(e, e0 + eb);
    for (int i = e0 + t; i < e1; i += 256) {
        int s = src[i], d = dst[i];
        int k = (s >> TSHIFT) * nbukd + (d >> 8);
        int p = atomicAdd(&cur[k], 1);
        coarse[p] = ((unsigned int)(d & 255) << 24) | (unsigned int)s;
    }
}

// ---------------- pass 4: fine sort within bucket -> rpt[t][node], col ----------------
__global__ __launch_bounds__(256) void bucket2_k(const unsigned int* __restrict__ coarse, const int* __restrict__ bbase,
                                                 int* __restrict__ rpt, int* __restrict__ col,
                                                 int n, int nbukd, int B, int T) {
    __shared__ int h[256];
    __shared__ int s[256];
    __shared__ int cur[256];
    int b = blockIdx.x, t = threadIdx.x;
    int e0 = bbase[b], e1 = bbase[b + 1];
    h[t] = 0;
    __syncthreads();
    for (int i = e0 + t; i < e1; i += 256) atomicAdd(&h[coarse[i] >> 24], 1);
    __syncthreads();
    int v = h[t];
    s[t] = v;
    __syncthreads();
    for (int st = 1; st < 256; st <<= 1) {
        int add = (t >= st) ? s[t - st] : 0;
        __syncthreads();
        s[t] += add;
        __syncthreads();
    }
    int excl = s[t] - v;
    int tt = b / nbukd;
    int db = b - tt * nbukd;
    int gnode = db * 256 + t;
    if (gnode < n) rpt[(size_t)tt * n + gnode] = e0 + excl;
    cur[t] = e0 + excl;
    __syncthreads();
    for (int i = e0 + t; i < e1; i += 256) {
        unsigned int pk = coarse[i];
        int p = atomicAdd(&cur[pk >> 24], 1);
        col[p] = (int)(pk & 0x00FFFFFFu);
    }
    if (b == B - 1 && t == 0) rpt[(size_t)T * n] = e1;
}

// ---------------- deg (from rpt diffs) -> dis ----------------
__global__ __launch_bounds__(256) void degdis_k(const int* __restrict__ rpt, float* __restrict__ dis, int n, int T) {
    int i = blockIdx.x * 256 + threadIdx.x;
    if (i >= n) return;
    int d = 0;
    for (int t = 0; t < T; t++) d += rpt[(size_t)t * n + i + 1] - rpt[(size_t)t * n + i];
    dis[i] = rsqrtf((float)d + 1.0f);
}

// ---------------- MFMA GEMM: C[r] = dis[r] * (A[r] @ W); A f32 (layer1) or bf16; C bf16 ----------------
template <bool INF32>
__global__ __launch_bounds__(256) void gemm_mfma_k(const void* __restrict__ Av, const float* __restrict__ W,
                                                   const float* __restrict__ dis, unsigned short* __restrict__ C,
                                                   int nrows) {
    __shared__ unsigned short WT[128 * 136];   // W^T[n][k], pad ld=136 to dodge bank conflicts
    int t = threadIdx.x;
    for (int i = t; i < 16384; i += 256) {
        int k = i >> 7, nn = i & 127;
        WT[nn * 136 + k] = f2bf(W[i]);
    }
    __syncthreads();
    int wave = t >> 6, lane = t & 63;
    int lm = lane & 15, lg = lane >> 4;      // lg in 0..3
    for (int m0 = blockIdx.x * 64; m0 < nrows; m0 += gridDim.x * 64) {
        int R = m0 + wave * 16;
        int arow = R + lm;
        if (arow >= nrows) arow = nrows - 1;
        f32x4 acc[8];
#pragma unroll
        for (int q = 0; q < 8; q++) acc[q] = (f32x4){0.f, 0.f, 0.f, 0.f};
#pragma unroll
        for (int kk = 0; kk < 4; kk++) {
            bf16x8 af;
            if constexpr (INF32) {
                const float4* ap = (const float4*)((const float*)Av + (size_t)arow * 128 + kk * 32 + lg * 8);
                float4 a0 = ap[0], a1 = ap[1];
                u32x4 au;
                au[0] = packbf2(a0.x, a0.y); au[1] = packbf2(a0.z, a0.w);
                au[2] = packbf2(a1.x, a1.y); au[3] = packbf2(a1.z, a1.w);
                af = __builtin_bit_cast(bf16x8, au);
            } else {
                const u32x4* ap = (const u32x4*)((const unsigned short*)Av + (size_t)arow * 128);
                af = __builtin_bit_cast(bf16x8, ap[kk * 4 + lg]);
            }
#pragma unroll
            for (int q = 0; q < 8; q++) {
                const u32x4* bp = (const u32x4*)(WT + (q * 16 + lm) * 136 + kk * 32 + lg * 8);
                bf16x8 bfr = __builtin_bit_cast(bf16x8, *bp);          // B[k][n=q*16+lm]
                acc[q] = __builtin_amdgcn_mfma_f32_16x16x32_bf16(af, bfr, acc[q], 0, 0, 0);
            }
        }
        float dsc[4];
#pragma unroll
        for (int i2 = 0; i2 < 4; i2++) {
            int r = R + lg * 4 + i2;
            dsc[i2] = (r < nrows) ? dis[r] : 0.f;
        }
#pragma unroll
        for (int i2 = 0; i2 < 4; i2++) {
            int r = R + lg * 4 + i2;
            if (r < nrows) {
                unsigned short* cp = C + (size_t)r * 128 + lm;
#pragma unroll
                for (int q = 0; q < 8; q++) cp[q * 16] = f2bf(acc[q][i2] * dsc[i2]);
            }
        }
    }
}

// ---------------- persistent tiled aggregation ----------------
// Exactly-resident grid; each wave owns KN consecutive nodes, acc in registers.
// Tile phase t: all waves gather only from h'[tile t] (4.2 MB -> per-XCD L2 resident).
template <int KN>
__global__ __launch_bounds__(256, 4) void agg_tiled_k(const unsigned short* __restrict__ h,
                                                      unsigned short* __restrict__ out,
                                                      const int* __restrict__ rpt, const int* __restrict__ col,
                                                      const float* __restrict__ dis, const float* __restrict__ bias,
                                                      int n, int T) {
    int wid  = (blockIdx.x * 256 + threadIdx.x) >> 6;   // global wave id
    int lane = threadIdx.x & 63;
    int node0 = wid * KN;
    if (node0 >= n) return;
    const unsigned int* hp = (const unsigned int*)h;    // bf16x2 elements, row stride 64
    float accx[KN], accy[KN];
#pragma unroll
    for (int i = 0; i < KN; i++) { accx[i] = 0.f; accy[i] = 0.f; }
    // self rows (streaming: wave's nodes are consecutive)
#pragma unroll
    for (int i = 0; i < KN; i++) {
        int nd = node0 + i;
        if (nd < n) {
            unsigned int v = hp[((size_t)nd << 6) + lane];
            accx[i] += bflo(v);
            accy[i] += bfhi(v);
        }
    }
    // tile-phased gather
    for (int t = 0; t < T; t++) {
        const int* rp = rpt + (size_t)t * n;
#pragma unroll
        for (int i = 0; i < KN; i++) {
            int nd = node0 + i;
            if (nd < n) {
                int e = rp[nd], e1 = rp[nd + 1];
                for (; e + 2 <= e1; e += 2) {
                    int c0 = col[e], c1 = col[e + 1];
                    unsigned int v0 = hp[((size_t)c0 << 6) + lane];
                    unsigned int v1 = hp[((size_t)c1 << 6) + lane];
                    accx[i] += bflo(v0) + bflo(v1);
                    accy[i] += bfhi(v0) + bfhi(v1);
                }
                if (e < e1) {
                    unsigned int v = hp[((size_t)col[e] << 6) + lane];
                    accx[i] += bflo(v);
                    accy[i] += bfhi(v);
                }
            }
        }
    }
    float2 b = ((const float2*)bias)[lane];
#pragma unroll
    for (int i = 0; i < KN; i++) {
        int nd = node0 + i;
        if (nd < n) {
            float d = dis[nd];
            ((unsigned int*)out)[((size_t)nd << 6) + lane] =
                packbf2(fmaxf(b.x + d * accx[i], 0.f), fmaxf(b.y + d * accy[i], 0.f));
        }
    }
}

// ---------------- fused global mean pool + classifier ----------------
__global__ __launch_bounds__(128) void pool_logits_k(const unsigned short* __restrict__ h, const int* __restrict__ batch,
                                                     const float* __restrict__ Wc, const float* __restrict__ bc,
                                                     float* __restrict__ logits, float* __restrict__ pooled,
                                                     int n, int nc) {
    __shared__ float pl[128];
    int g = blockIdx.x;
    int j = threadIdx.x;
    int lo = 0, hi = n;
    while (lo < hi) { int mid = (lo + hi) >> 1; if (batch[mid] < g) lo = mid + 1; else hi = mid; }
    int start = lo;
    hi = n;
    while (lo < hi) { int mid = (lo + hi) >> 1; if (batch[mid] < g + 1) lo = mid + 1; else hi = mid; }
    int end = lo;
    float acc = 0.f;
    for (int r = start; r < end; r++) acc += bf2f(h[(size_t)r * 128 + j]);
    float pv = acc / fmaxf((float)(end - start), 1.0f);
    pooled[(size_t)g * 128 + j] = pv;
    pl[j] = pv;
    __syncthreads();
    if (j < nc) {
        float a = bc[j];
#pragma unroll 8
        for (int k = 0; k < 128; k++) a += pl[k] * Wc[k * nc + j];
        logits[(size_t)g * nc + j] = a;
    }
}

extern "C" void kernel_launch(void* const* d_in, const int* in_sizes, int n_in,
                              void* d_out, int out_size, void* d_ws, size_t ws_size,
                              hipStream_t stream) {
    const float* x     = (const float*)d_in[0];
    const int*   ei    = (const int*)d_in[1];
    const int*   batch = (const int*)d_in[2];
    const float* W1    = (const float*)d_in[3];
    const float* b1    = (const float*)d_in[4];
    const float* W2    = (const float*)d_in[5];
    const float* b2    = (const float*)d_in[6];
    const float* Wc    = (const float*)d_in[7];
    const float* bc    = (const float*)d_in[8];
    float* out = (float*)d_out;

    const int N = in_sizes[0] / 128;
    const int E = in_sizes[1] / 2;
    const int NC = 10;
    const int G = out_size / (NC + 128);

    const int* src = ei;
    const int* dst = ei + E;

    const int EB    = 16384;
    const int NBLK  = (E + EB - 1) / EB;
    const int NBUKD = (N + 255) / 256;            // dst blocks (391)
    const int T     = (N + (1 << TSHIFT) - 1) >> TSHIFT;   // src tiles (7)
    const int B     = T * NBUKD;                  // buckets (2737), must be <= 4096

    // workspace carve (256B aligned)
    char* wbase = (char*)d_ws;
    size_t off = 0;
    auto alloc = [&](size_t bytes) -> void* {
        void* p = wbase + off;
        off = (off + bytes + 255) & ~(size_t)255;
        return p;
    };
    float* dis   = (float*)alloc((size_t)N * 4);
    int*   rpt   = (int*)alloc(((size_t)T * N + 1) * 4);
    int*   hist  = (int*)alloc((size_t)B * NBLK * 4);
    int*   btot  = (int*)alloc((size_t)B * 4);
    int*   bbase = (int*)alloc((size_t)(B + 1) * 4);
    unsigned int* coarse = (unsigned int*)alloc((size_t)E * 4);
    int*   col   = (int*)alloc((size_t)E * 4);
    unsigned short* bufT = (unsigned short*)alloc((size_t)N * 128 * 2);
    unsigned short* bufH = (unsigned short*)alloc((size_t)N * 128 * 2);

    // --- CSR build keyed by (src-tile, dst) ---
    hist2_k<<<NBLK, 256, 0, stream>>>(src, dst, hist, E, B, NBUKD, NBLK, EB);
    scanA_k<<<(B * 64 + 255) / 256, 256, 0, stream>>>(hist, btot, B, NBLK);
    scanBbig_k<<<1, 512, 0, stream>>>(btot, bbase, B);
    scatter2_k<<<NBLK, 256, 0, stream>>>(src, dst, hist, bbase, coarse, E, B, NBUKD, NBLK, EB);
    bucket2_k<<<B, 256, 0, stream>>>(coarse, bbase, rpt, col, N, NBUKD, B, T);
    degdis_k<<<(N + 255) / 256, 256, 0, stream>>>(rpt, dis, N, T);

    // --- layers ---
    constexpr int KN = 25;
    const int aggBlocks = (N + KN * 4 - 1) / (KN * 4);   // 1000 -> exactly resident at 4 blocks/CU
    gemm_mfma_k<true><<<512, 256, 0, stream>>>(x, W1, dis, bufT, N);
    agg_tiled_k<KN><<<aggBlocks, 256, 0, stream>>>(bufT, bufH, rpt, col, dis, b1, N, T);
    gemm_mfma_k<false><<<512, 256, 0, stream>>>(bufH, W2, dis, bufT, N);
    agg_tiled_k<KN><<<aggBlocks, 256, 0, stream>>>(bufT, bufH, rpt, col, dis, b2, N, T);

    float* pooled = out + (size_t)G * NC;
    pool_logits_k<<<G, 128, 0, stream>>>(bufH, batch, Wc, bc, out, pooled, N, NC);
}

// Round 8
// 587.251 us; speedup vs baseline: 1.4060x; 1.4060x over previous
//
#include <hip/hip_runtime.h>
#include <hip/hip_bf16.h>

typedef short bf16x8 __attribute__((ext_vector_type(8)));
typedef float f32x4 __attribute__((ext_vector_type(4)));
typedef unsigned int u32x4 __attribute__((ext_vector_type(4)));

__device__ __forceinline__ unsigned short f2bf(float f) {
    unsigned int u = __float_as_uint(f);
    unsigned int r = u + 0x7fffu + ((u >> 16) & 1u);
    return (unsigned short)(r >> 16);
}
__device__ __forceinline__ float bf2f(unsigned short b) {
    return __uint_as_float(((unsigned int)b) << 16);
}
__device__ __forceinline__ unsigned int packbf2(float lo, float hi) {
    return ((unsigned int)f2bf(hi) << 16) | (unsigned int)f2bf(lo);
}
__device__ __forceinline__ float bflo(unsigned int v) { return __uint_as_float(v << 16); }
__device__ __forceinline__ float bfhi(unsigned int v) { return __uint_as_float(v & 0xffff0000u); }

#define TSHIFT 14   // src tile = 16384 nodes (4.2 MB of h' rows)

// ---------------- pass 1: per-block histogram over (srctile, dstblock) buckets ----------------
__global__ __launch_bounds__(256) void hist2_k(const int* __restrict__ src, const int* __restrict__ dst,
                                               int* __restrict__ hist, int e, int B, int nbukd,
                                               int nblk, int eb) {
    __shared__ int lh[4096];
    int blk = blockIdx.x, t = threadIdx.x;
    for (int j = t; j < 4096; j += 256) lh[j] = 0;
    __syncthreads();
    int e0 = blk * eb, e1 = min(e, e0 + eb);
    for (int i = e0 + t; i < e1; i += 256) {
        int k = (src[i] >> TSHIFT) * nbukd + (dst[i] >> 8);
        atomicAdd(&lh[k], 1);
    }
    __syncthreads();
    for (int j = t; j < B; j += 256) hist[(size_t)j * nblk + blk] = lh[j];
}

// ---------------- pass 2a: per-bucket exclusive scan over blocks; bucket totals ----------------
__global__ __launch_bounds__(256) void scanA_k(int* __restrict__ hist, int* __restrict__ btot, int nbuk, int nblk) {
    int w = (blockIdx.x * 256 + threadIdx.x) >> 6;
    int lane = threadIdx.x & 63;
    if (w >= nbuk) return;
    size_t base = (size_t)w * nblk;
    int run = 0;
    for (int c = 0; c < nblk; c += 64) {
        int i = c + lane;
        int v = (i < nblk) ? hist[base + i] : 0;
        int orig = v;
        for (int d = 1; d < 64; d <<= 1) { int u = __shfl_up(v, d); if (lane >= d) v += u; }
        if (i < nblk) hist[base + i] = run + v - orig;   // exclusive within bucket
        run += __shfl(v, 63);
    }
    if (lane == 0) btot[w] = run;
}

// ---------------- pass 2b: multi-chunk scan of bucket totals -> bucket bases ----------------
__global__ __launch_bounds__(512) void scanBbig_k(const int* __restrict__ btot, int* __restrict__ bbase, int B) {
    __shared__ int s[512];
    __shared__ int carry;
    int t = threadIdx.x;
    if (t == 0) carry = 0;
    __syncthreads();
    for (int c0 = 0; c0 < B; c0 += 512) {
        int idx = c0 + t;
        int v = (idx < B) ? btot[idx] : 0;
        s[t] = v;
        __syncthreads();
        for (int st = 1; st < 512; st <<= 1) {
            int add = (t >= st) ? s[t - st] : 0;
            __syncthreads();
            s[t] += add;
            __syncthreads();
        }
        if (idx < B) bbase[idx] = carry + s[t] - v;
        __syncthreads();
        if (t == 511) carry += s[511];
        __syncthreads();
    }
    if (t == 0) bbase[B] = carry;
}

// ---------------- pass 3: scatter into (srctile, dstblock) bucket regions ----------------
__global__ __launch_bounds__(256) void scatter2_k(const int* __restrict__ src, const int* __restrict__ dst,
                                                  const int* __restrict__ hist, const int* __restrict__ bbase,
                                                  unsigned int* __restrict__ coarse, int e, int B, int nbukd,
                                                  int nblk, int eb) {
    __shared__ int cur[4096];
    int blk = blockIdx.x, t = threadIdx.x;
    for (int j = t; j < B; j += 256) cur[j] = bbase[j] + hist[(size_t)j * nblk + blk];
    __syncthreads();
    int e0 = blk * eb, e1 = min(e, e0 + eb);
    for (int i = e0 + t; i < e1; i += 256) {
        int s = src[i], d = dst[i];
        int k = (s >> TSHIFT) * nbukd + (d >> 8);
        int p = atomicAdd(&cur[k], 1);
        coarse[p] = ((unsigned int)(d & 255) << 24) | (unsigned int)s;
    }
}

// ---------------- pass 4: fine sort within bucket -> rpt[t][node] (stride n+1), col ----------------
__global__ __launch_bounds__(256) void bucket2_k(const unsigned int* __restrict__ coarse, const int* __restrict__ bbase,
                                                 int* __restrict__ rpt, int* __restrict__ col,
                                                 int n, int nbukd, int B, int T) {
    __shared__ int h[256];
    __shared__ int s[256];
    __shared__ int cur[256];
    int b = blockIdx.x, t = threadIdx.x;
    int e0 = bbase[b], e1 = bbase[b + 1];
    h[t] = 0;
    __syncthreads();
    for (int i = e0 + t; i < e1; i += 256) atomicAdd(&h[coarse[i] >> 24], 1);
    __syncthreads();
    int v = h[t];
    s[t] = v;
    __syncthreads();
    for (int st = 1; st < 256; st <<= 1) {
        int add = (t >= st) ? s[t - st] : 0;
        __syncthreads();
        s[t] += add;
        __syncthreads();
    }
    int excl = s[t] - v;
    int tt = b / nbukd;
    int db = b - tt * nbukd;
    int gnode = db * 256 + t;
    if (gnode < n) rpt[(size_t)tt * (n + 1) + gnode] = e0 + excl;
    if (db == nbukd - 1 && t == 0) rpt[(size_t)tt * (n + 1) + n] = e1;   // end-of-tile sentinel
    cur[t] = e0 + excl;
    __syncthreads();
    for (int i = e0 + t; i < e1; i += 256) {
        unsigned int pk = coarse[i];
        int p = atomicAdd(&cur[pk >> 24], 1);
        col[p] = (int)(pk & 0x00FFFFFFu);
    }
}

// ---------------- deg (from rpt diffs) -> dis ----------------
__global__ __launch_bounds__(256) void degdis_k(const int* __restrict__ rpt, float* __restrict__ dis, int n, int T) {
    int i = blockIdx.x * 256 + threadIdx.x;
    if (i >= n) return;
    int d = 0;
    for (int t = 0; t < T; t++) {
        const int* rp = rpt + (size_t)t * (n + 1);
        d += rp[i + 1] - rp[i];
    }
    dis[i] = rsqrtf((float)d + 1.0f);
}

// ---------------- MFMA GEMM: C[r] = dis[r] * (A[r] @ W); A f32 (layer1) or bf16; C bf16 ----------------
template <bool INF32>
__global__ __launch_bounds__(256) void gemm_mfma_k(const void* __restrict__ Av, const float* __restrict__ W,
                                                   const float* __restrict__ dis, unsigned short* __restrict__ C,
                                                   int nrows) {
    __shared__ unsigned short WT[128 * 136];   // W^T[n][k], pad ld=136 to dodge bank conflicts
    int t = threadIdx.x;
    for (int i = t; i < 16384; i += 256) {
        int k = i >> 7, nn = i & 127;
        WT[nn * 136 + k] = f2bf(W[i]);
    }
    __syncthreads();
    int wave = t >> 6, lane = t & 63;
    int lm = lane & 15, lg = lane >> 4;      // lg in 0..3
    for (int m0 = blockIdx.x * 64; m0 < nrows; m0 += gridDim.x * 64) {
        int R = m0 + wave * 16;
        int arow = R + lm;
        if (arow >= nrows) arow = nrows - 1;
        f32x4 acc[8];
#pragma unroll
        for (int q = 0; q < 8; q++) acc[q] = (f32x4){0.f, 0.f, 0.f, 0.f};
#pragma unroll
        for (int kk = 0; kk < 4; kk++) {
            bf16x8 af;
            if constexpr (INF32) {
                const float4* ap = (const float4*)((const float*)Av + (size_t)arow * 128 + kk * 32 + lg * 8);
                float4 a0 = ap[0], a1 = ap[1];
                u32x4 au;
                au[0] = packbf2(a0.x, a0.y); au[1] = packbf2(a0.z, a0.w);
                au[2] = packbf2(a1.x, a1.y); au[3] = packbf2(a1.z, a1.w);
                af = __builtin_bit_cast(bf16x8, au);
            } else {
                const u32x4* ap = (const u32x4*)((const unsigned short*)Av + (size_t)arow * 128);
                af = __builtin_bit_cast(bf16x8, ap[kk * 4 + lg]);
            }
#pragma unroll
            for (int q = 0; q < 8; q++) {
                const u32x4* bp = (const u32x4*)(WT + (q * 16 + lm) * 136 + kk * 32 + lg * 8);
                bf16x8 bfr = __builtin_bit_cast(bf16x8, *bp);          // B[k][n=q*16+lm]
                acc[q] = __builtin_amdgcn_mfma_f32_16x16x32_bf16(af, bfr, acc[q], 0, 0, 0);
            }
        }
        float dsc[4];
#pragma unroll
        for (int i2 = 0; i2 < 4; i2++) {
            int r = R + lg * 4 + i2;
            dsc[i2] = (r < nrows) ? dis[r] : 0.f;
        }
#pragma unroll
        for (int i2 = 0; i2 < 4; i2++) {
            int r = R + lg * 4 + i2;
            if (r < nrows) {
                unsigned short* cp = C + (size_t)r * 128 + lm;
#pragma unroll
                for (int q = 0; q < 8; q++) cp[q * 16] = f2bf(acc[q][i2] * dsc[i2]);
            }
        }
    }
}

// ---------------- persistent tiled aggregation (v2: vector rpt loads, 4-wide batches) ----------------
// Exactly-resident grid; wave owns KN consecutive nodes, acc in registers.
// Tile phase t: gathers only touch h'[tile t] (4.2 MB -> per-XCD L2 resident).
template <int KN>
__global__ __launch_bounds__(256, 6) void agg_tiled_k(const unsigned short* __restrict__ h,
                                                      unsigned short* __restrict__ out,
                                                      const int* __restrict__ rpt, const int* __restrict__ col,
                                                      const float* __restrict__ dis, const float* __restrict__ bias,
                                                      int n, int T) {
    int wid  = (blockIdx.x * 256 + threadIdx.x) >> 6;   // global wave id
    int lane = threadIdx.x & 63;
    int node0 = wid * KN;
    if (node0 >= n) return;
    const unsigned int* hp = (const unsigned int*)h;    // bf16x2 elements, row stride 64
    float accx[KN], accy[KN];
    // self rows (consecutive -> streaming)
#pragma unroll
    for (int i = 0; i < KN; i++) {
        int nd = node0 + i;
        unsigned int v = (nd < n) ? hp[((size_t)nd << 6) + lane] : 0u;
        accx[i] = bflo(v);
        accy[i] = bfhi(v);
    }
    // tile-phased gather
    for (int t = 0; t < T; t++) {
        const int* rp = rpt + (size_t)t * (n + 1);
        // lanes 0..KN hold this wave's KN+1 segment boundaries for tile t (one vector load)
        int idx = node0 + lane;
        if (idx > n) idx = n;
        int rv = (lane <= KN) ? rp[idx] : 0;
#pragma unroll
        for (int i = 0; i < KN; i++) {
            int e  = __shfl(rv, i);
            int e1 = __shfl(rv, i + 1);
            for (; e + 4 <= e1; e += 4) {
                int c0 = col[e], c1 = col[e + 1], c2 = col[e + 2], c3 = col[e + 3];
                unsigned int v0 = hp[((size_t)c0 << 6) + lane];
                unsigned int v1 = hp[((size_t)c1 << 6) + lane];
                unsigned int v2 = hp[((size_t)c2 << 6) + lane];
                unsigned int v3 = hp[((size_t)c3 << 6) + lane];
                accx[i] += bflo(v0) + bflo(v1) + bflo(v2) + bflo(v3);
                accy[i] += bfhi(v0) + bfhi(v1) + bfhi(v2) + bfhi(v3);
            }
            for (; e < e1; e++) {
                unsigned int v = hp[((size_t)col[e] << 6) + lane];
                accx[i] += bflo(v);
                accy[i] += bfhi(v);
            }
        }
    }
    float2 b = ((const float2*)bias)[lane];
#pragma unroll
    for (int i = 0; i < KN; i++) {
        int nd = node0 + i;
        if (nd < n) {
            float d = dis[nd];
            ((unsigned int*)out)[((size_t)nd << 6) + lane] =
                packbf2(fmaxf(b.x + d * accx[i], 0.f), fmaxf(b.y + d * accy[i], 0.f));
        }
    }
}

// ---------------- fused global mean pool + classifier ----------------
__global__ __launch_bounds__(128) void pool_logits_k(const unsigned short* __restrict__ h, const int* __restrict__ batch,
                                                     const float* __restrict__ Wc, const float* __restrict__ bc,
                                                     float* __restrict__ logits, float* __restrict__ pooled,
                                                     int n, int nc) {
    __shared__ float pl[128];
    int g = blockIdx.x;
    int j = threadIdx.x;
    int lo = 0, hi = n;
    while (lo < hi) { int mid = (lo + hi) >> 1; if (batch[mid] < g) lo = mid + 1; else hi = mid; }
    int start = lo;
    hi = n;
    while (lo < hi) { int mid = (lo + hi) >> 1; if (batch[mid] < g + 1) lo = mid + 1; else hi = mid; }
    int end = lo;
    float acc = 0.f;
    for (int r = start; r < end; r++) acc += bf2f(h[(size_t)r * 128 + j]);
    float pv = acc / fmaxf((float)(end - start), 1.0f);
    pooled[(size_t)g * 128 + j] = pv;
    pl[j] = pv;
    __syncthreads();
    if (j < nc) {
        float a = bc[j];
#pragma unroll 8
        for (int k = 0; k < 128; k++) a += pl[k] * Wc[k * nc + j];
        logits[(size_t)g * nc + j] = a;
    }
}

extern "C" void kernel_launch(void* const* d_in, const int* in_sizes, int n_in,
                              void* d_out, int out_size, void* d_ws, size_t ws_size,
                              hipStream_t stream) {
    const float* x     = (const float*)d_in[0];
    const int*   ei    = (const int*)d_in[1];
    const int*   batch = (const int*)d_in[2];
    const float* W1    = (const float*)d_in[3];
    const float* b1    = (const float*)d_in[4];
    const float* W2    = (const float*)d_in[5];
    const float* b2    = (const float*)d_in[6];
    const float* Wc    = (const float*)d_in[7];
    const float* bc    = (const float*)d_in[8];
    float* out = (float*)d_out;

    const int N = in_sizes[0] / 128;
    const int E = in_sizes[1] / 2;
    const int NC = 10;
    const int G = out_size / (NC + 128);

    const int* src = ei;
    const int* dst = ei + E;

    const int EB    = 16384;
    const int NBLK  = (E + EB - 1) / EB;
    const int NBUKD = (N + 255) / 256;                     // dst blocks (391)
    const int T     = (N + (1 << TSHIFT) - 1) >> TSHIFT;   // src tiles (7)
    const int B     = T * NBUKD;                           // buckets (2737) <= 4096

    // workspace carve (256B aligned)
    char* wbase = (char*)d_ws;
    size_t off = 0;
    auto alloc = [&](size_t bytes) -> void* {
        void* p = wbase + off;
        off = (off + bytes + 255) & ~(size_t)255;
        return p;
    };
    float* dis   = (float*)alloc((size_t)N * 4);
    int*   rpt   = (int*)alloc((size_t)T * (N + 1) * 4);
    int*   hist  = (int*)alloc((size_t)B * NBLK * 4);
    int*   btot  = (int*)alloc((size_t)B * 4);
    int*   bbase = (int*)alloc((size_t)(B + 1) * 4);
    unsigned int* coarse = (unsigned int*)alloc((size_t)E * 4);
    int*   col   = (int*)alloc((size_t)E * 4);
    unsigned short* bufT = (unsigned short*)alloc((size_t)N * 128 * 2);
    unsigned short* bufH = (unsigned short*)alloc((size_t)N * 128 * 2);

    // --- CSR build keyed by (src-tile, dst) ---
    hist2_k<<<NBLK, 256, 0, stream>>>(src, dst, hist, E, B, NBUKD, NBLK, EB);
    scanA_k<<<(B * 64 + 255) / 256, 256, 0, stream>>>(hist, btot, B, NBLK);
    scanBbig_k<<<1, 512, 0, stream>>>(btot, bbase, B);
    scatter2_k<<<NBLK, 256, 0, stream>>>(src, dst, hist, bbase, coarse, E, B, NBUKD, NBLK, EB);
    bucket2_k<<<B, 256, 0, stream>>>(coarse, bbase, rpt, col, N, NBUKD, B, T);
    degdis_k<<<(N + 255) / 256, 256, 0, stream>>>(rpt, dis, N, T);

    // --- layers ---
    constexpr int KN = 17;
    const int aggBlocks = (N + KN * 4 - 1) / (KN * 4);   // 1471 -> all resident at 6 blocks/CU
    gemm_mfma_k<true><<<512, 256, 0, stream>>>(x, W1, dis, bufT, N);
    agg_tiled_k<KN><<<aggBlocks, 256, 0, stream>>>(bufT, bufH, rpt, col, dis, b1, N, T);
    gemm_mfma_k<false><<<512, 256, 0, stream>>>(bufH, W2, dis, bufT, N);
    agg_tiled_k<KN><<<aggBlocks, 256, 0, stream>>>(bufT, bufH, rpt, col, dis, b2, N, T);

    float* pooled = out + (size_t)G * NC;
    pool_logits_k<<<G, 128, 0, stream>>>(bufH, batch, Wc, bc, out, pooled, N, NC);
}

// Round 9
// 420.618 us; speedup vs baseline: 1.9630x; 1.3962x over previous
//
#include <hip/hip_runtime.h>
#include <hip/hip_bf16.h>

typedef short bf16x8 __attribute__((ext_vector_type(8)));
typedef float f32x4 __attribute__((ext_vector_type(4)));
typedef unsigned int u32x4 __attribute__((ext_vector_type(4)));

__device__ __forceinline__ unsigned short f2bf(float f) {
    unsigned int u = __float_as_uint(f);
    unsigned int r = u + 0x7fffu + ((u >> 16) & 1u);
    return (unsigned short)(r >> 16);
}
__device__ __forceinline__ float bf2f(unsigned short b) {
    return __uint_as_float(((unsigned int)b) << 16);
}
__device__ __forceinline__ unsigned int packbf2(float lo, float hi) {
    return ((unsigned int)f2bf(hi) << 16) | (unsigned int)f2bf(lo);
}

// ---------------- pass 1: per-block bucket histogram (bucket = dst>>8) ----------------
__global__ __launch_bounds__(256) void hist_k(const int* __restrict__ dst, int* __restrict__ hist,
                                              int e, int nbuk, int nblk, int eb) {
    __shared__ int lh[512];
    int blk = blockIdx.x, t = threadIdx.x;
    for (int j = t; j < nbuk; j += 256) lh[j] = 0;
    __syncthreads();
    int e0 = blk * eb, e1 = min(e, e0 + eb);
    for (int i = e0 + t; i < e1; i += 256) atomicAdd(&lh[dst[i] >> 8], 1);
    __syncthreads();
    for (int j = t; j < nbuk; j += 256) hist[(size_t)j * nblk + blk] = lh[j];
}

// ---------------- pass 2a: per-bucket exclusive scan over blocks; bucket totals ----------------
__global__ __launch_bounds__(256) void scanA_k(int* __restrict__ hist, int* __restrict__ btot, int nbuk, int nblk) {
    int w = (blockIdx.x * 256 + threadIdx.x) >> 6;
    int lane = threadIdx.x & 63;
    if (w >= nbuk) return;
    size_t base = (size_t)w * nblk;
    int run = 0;
    for (int c = 0; c < nblk; c += 64) {
        int i = c + lane;
        int v = (i < nblk) ? hist[base + i] : 0;
        int orig = v;
        for (int d = 1; d < 64; d <<= 1) { int u = __shfl_up(v, d); if (lane >= d) v += u; }
        if (i < nblk) hist[base + i] = run + v - orig;   // exclusive within bucket
        run += __shfl(v, 63);
    }
    if (lane == 0) btot[w] = run;
}

// ---------------- pass 2b: scan bucket totals -> bucket bases ----------------
__global__ __launch_bounds__(512) void scanB_k(const int* __restrict__ btot, int* __restrict__ bbase, int nbuk) {
    __shared__ int s[512];
    int t = threadIdx.x;
    int v = (t < nbuk) ? btot[t] : 0;
    s[t] = v;
    __syncthreads();
    for (int st = 1; st < 512; st <<= 1) {
        int add = (t >= st) ? s[t - st] : 0;
        __syncthreads();
        s[t] += add;
        __syncthreads();
    }
    if (t < nbuk) bbase[t] = s[t] - v;
    if (t == nbuk - 1) bbase[nbuk] = s[t];
}

// ---------------- pass 3: coarse scatter into bucket regions (packed dstlocal|src) ----------------
__global__ __launch_bounds__(256) void scatter_k(const int* __restrict__ src, const int* __restrict__ dst,
                                                 const int* __restrict__ hist, const int* __restrict__ bbase,
                                                 unsigned int* __restrict__ coarse, int e, int nbuk, int nblk, int eb) {
    __shared__ int cur[512];
    int blk = blockIdx.x, t = threadIdx.x;
    for (int j = t; j < nbuk; j += 256) cur[j] = bbase[j] + hist[(size_t)j * nblk + blk];
    __syncthreads();
    int e0 = blk * eb, e1 = min(e, e0 + eb);
    for (int i = e0 + t; i < e1; i += 256) {
        int s = src[i], d = dst[i];
        int bk = d >> 8;
        int p = atomicAdd(&cur[bk], 1);
        coarse[p] = ((unsigned int)(d & 255) << 24) | (unsigned int)s;
    }
}

// ---------------- pass 4: per-bucket fine sort -> row_ptr, col, dis ----------------
__global__ __launch_bounds__(256) void bucket_k(const unsigned int* __restrict__ coarse, const int* __restrict__ bbase,
                                                float* __restrict__ dis, int* __restrict__ row_ptr, int* __restrict__ col,
                                                int n, int nbuk, int e) {
    __shared__ int h[256];
    __shared__ int s[256];
    __shared__ int cur[256];
    int b = blockIdx.x, t = threadIdx.x;
    int e0 = bbase[b], e1 = bbase[b + 1];
    h[t] = 0;
    __syncthreads();
    for (int i = e0 + t; i < e1; i += 256) atomicAdd(&h[coarse[i] >> 24], 1);
    __syncthreads();
    int v = h[t];
    s[t] = v;
    __syncthreads();
    for (int st = 1; st < 256; st <<= 1) {
        int add = (t >= st) ? s[t - st] : 0;
        __syncthreads();
        s[t] += add;
        __syncthreads();
    }
    int excl = s[t] - v;
    int node = b * 256 + t;
    if (node < n) {
        row_ptr[node] = e0 + excl;
        dis[node] = rsqrtf((float)v + 1.0f);
    }
    cur[t] = e0 + excl;
    __syncthreads();
    for (int i = e0 + t; i < e1; i += 256) {
        unsigned int pk = coarse[i];
        int p = atomicAdd(&cur[pk >> 24], 1);
        col[p] = (int)(pk & 0x00FFFFFFu);
    }
    if (b == nbuk - 1 && t == 0) row_ptr[n] = e;
}

// ---------------- MFMA GEMM: C[r] = dis[r] * (A[r] @ W); A f32 (layer1) or bf16; C bf16 ----------------
template <bool INF32>
__global__ __launch_bounds__(256) void gemm_mfma_k(const void* __restrict__ Av, const float* __restrict__ W,
                                                   const float* __restrict__ dis, unsigned short* __restrict__ C,
                                                   int nrows) {
    __shared__ unsigned short WT[128 * 136];   // W^T[n][k], pad ld=136 to dodge bank conflicts
    int t = threadIdx.x;
    for (int i = t; i < 16384; i += 256) {
        int k = i >> 7, nn = i & 127;
        WT[nn * 136 + k] = f2bf(W[i]);
    }
    __syncthreads();
    int wave = t >> 6, lane = t & 63;
    int lm = lane & 15, lg = lane >> 4;      // lg in 0..3
    for (int m0 = blockIdx.x * 64; m0 < nrows; m0 += gridDim.x * 64) {
        int R = m0 + wave * 16;
        int arow = R + lm;
        if (arow >= nrows) arow = nrows - 1;
        f32x4 acc[8];
#pragma unroll
        for (int q = 0; q < 8; q++) acc[q] = (f32x4){0.f, 0.f, 0.f, 0.f};
#pragma unroll
        for (int kk = 0; kk < 4; kk++) {
            bf16x8 af;
            if constexpr (INF32) {
                const float4* ap = (const float4*)((const float*)Av + (size_t)arow * 128 + kk * 32 + lg * 8);
                float4 a0 = ap[0], a1 = ap[1];
                u32x4 au;
                au[0] = packbf2(a0.x, a0.y); au[1] = packbf2(a0.z, a0.w);
                au[2] = packbf2(a1.x, a1.y); au[3] = packbf2(a1.z, a1.w);
                af = __builtin_bit_cast(bf16x8, au);
            } else {
                const u32x4* ap = (const u32x4*)((const unsigned short*)Av + (size_t)arow * 128);
                af = __builtin_bit_cast(bf16x8, ap[kk * 4 + lg]);
            }
#pragma unroll
            for (int q = 0; q < 8; q++) {
                const u32x4* bp = (const u32x4*)(WT + (q * 16 + lm) * 136 + kk * 32 + lg * 8);
                bf16x8 bfr = __builtin_bit_cast(bf16x8, *bp);          // B[k][n=q*16+lm]
                acc[q] = __builtin_amdgcn_mfma_f32_16x16x32_bf16(af, bfr, acc[q], 0, 0, 0);
            }
        }
        float dsc[4];
#pragma unroll
        for (int i2 = 0; i2 < 4; i2++) {
            int r = R + lg * 4 + i2;
            dsc[i2] = (r < nrows) ? dis[r] : 0.f;
        }
#pragma unroll
        for (int i2 = 0; i2 < 4; i2++) {
            int r = R + lg * 4 + i2;
            if (r < nrows) {
                unsigned short* cp = C + (size_t)r * 128 + lm;
#pragma unroll
                for (int q = 0; q < 8; q++) cp[q * 16] = f2bf(acc[q][i2] * dsc[i2]);
            }
        }
    }
}

// ---------------- aggregation: out[n] = relu(b + dis[n]*(h'[n] + sum h'[col[e]]))
// wave = 1 node; 4 edge-streams x 16 lanes; each lane gathers 16 B; 4-deep unroll per stream
__global__ __launch_bounds__(256, 8) void agg_k(const unsigned short* __restrict__ h, unsigned short* __restrict__ out,
                                                const int* __restrict__ row_ptr, const int* __restrict__ col,
                                                const float* __restrict__ dis, const float* __restrict__ bias, int n) {
    int wid  = (blockIdx.x * 256 + threadIdx.x) >> 6;
    int lane = threadIdx.x & 63;
    if (wid >= n) return;
    int g = lane >> 4;                 // edge stream 0..3
    int s = lane & 15;                 // 16B chunk within 256B row
    const char* hb = (const char*)h;
    unsigned int soff = (unsigned int)(s << 4);
    float acc0 = 0.f, acc1 = 0.f, acc2 = 0.f, acc3 = 0.f;
    float acc4 = 0.f, acc5 = 0.f, acc6 = 0.f, acc7 = 0.f;
#define ACCUM(v)                                                                              \
    acc0 += __uint_as_float((v)[0] << 16); acc1 += __uint_as_float((v)[0] & 0xffff0000u);     \
    acc2 += __uint_as_float((v)[1] << 16); acc3 += __uint_as_float((v)[1] & 0xffff0000u);     \
    acc4 += __uint_as_float((v)[2] << 16); acc5 += __uint_as_float((v)[2] & 0xffff0000u);     \
    acc6 += __uint_as_float((v)[3] << 16); acc7 += __uint_as_float((v)[3] & 0xffff0000u);
    if (g == 0) {   // self-loop row
        u32x4 v = *(const u32x4*)(hb + (((unsigned int)wid << 8) + soff));
        ACCUM(v)
    }
    int e = row_ptr[wid] + g, e1 = row_ptr[wid + 1];
    // main loop: 4 edges per stream in flight (16 rows / 4 KB per wave)
    for (; e + 12 < e1; e += 16) {
        int c0 = col[e], c1 = col[e + 4], c2 = col[e + 8], c3 = col[e + 12];
        u32x4 v0 = *(const u32x4*)(hb + (((unsigned int)c0 << 8) + soff));
        u32x4 v1 = *(const u32x4*)(hb + (((unsigned int)c1 << 8) + soff));
        u32x4 v2 = *(const u32x4*)(hb + (((unsigned int)c2 << 8) + soff));
        u32x4 v3 = *(const u32x4*)(hb + (((unsigned int)c3 << 8) + soff));
        ACCUM(v0)
        ACCUM(v1)
        ACCUM(v2)
        ACCUM(v3)
    }
    for (; e < e1; e += 4) {
        u32x4 v = *(const u32x4*)(hb + (((unsigned int)col[e] << 8) + soff));
        ACCUM(v)
    }
#undef ACCUM
    // combine the 4 edge-streams (lane bits 4,5)
#define RED(a) a += __shfl_xor(a, 16); a += __shfl_xor(a, 32);
    RED(acc0) RED(acc1) RED(acc2) RED(acc3) RED(acc4) RED(acc5) RED(acc6) RED(acc7)
#undef RED
    if (g == 0) {
        float d = dis[wid];
        const float4* bp = (const float4*)bias;
        float4 ba = bp[2 * s], bb = bp[2 * s + 1];
        u32x4 r;
        r[0] = packbf2(fmaxf(ba.x + d * acc0, 0.f), fmaxf(ba.y + d * acc1, 0.f));
        r[1] = packbf2(fmaxf(ba.z + d * acc2, 0.f), fmaxf(ba.w + d * acc3, 0.f));
        r[2] = packbf2(fmaxf(bb.x + d * acc4, 0.f), fmaxf(bb.y + d * acc5, 0.f));
        r[3] = packbf2(fmaxf(bb.z + d * acc6, 0.f), fmaxf(bb.w + d * acc7, 0.f));
        *(u32x4*)((char*)out + (((unsigned int)wid << 8) + soff)) = r;
    }
}

// ---------------- fused global mean pool + classifier ----------------
__global__ __launch_bounds__(128) void pool_logits_k(const unsigned short* __restrict__ h, const int* __restrict__ batch,
                                                     const float* __restrict__ Wc, const float* __restrict__ bc,
                                                     float* __restrict__ logits, float* __restrict__ pooled,
                                                     int n, int nc) {
    __shared__ float pl[128];
    int g = blockIdx.x;
    int j = threadIdx.x;
    int lo = 0, hi = n;
    while (lo < hi) { int mid = (lo + hi) >> 1; if (batch[mid] < g) lo = mid + 1; else hi = mid; }
    int start = lo;
    hi = n;
    while (lo < hi) { int mid = (lo + hi) >> 1; if (batch[mid] < g + 1) lo = mid + 1; else hi = mid; }
    int end = lo;
    float acc = 0.f;
    for (int r = start; r < end; r++) acc += bf2f(h[(size_t)r * 128 + j]);
    float pv = acc / fmaxf((float)(end - start), 1.0f);
    pooled[(size_t)g * 128 + j] = pv;
    pl[j] = pv;
    __syncthreads();
    if (j < nc) {
        float a = bc[j];
#pragma unroll 8
        for (int k = 0; k < 128; k++) a += pl[k] * Wc[k * nc + j];
        logits[(size_t)g * nc + j] = a;
    }
}

extern "C" void kernel_launch(void* const* d_in, const int* in_sizes, int n_in,
                              void* d_out, int out_size, void* d_ws, size_t ws_size,
                              hipStream_t stream) {
    const float* x     = (const float*)d_in[0];
    const int*   ei    = (const int*)d_in[1];
    const int*   batch = (const int*)d_in[2];
    const float* W1    = (const float*)d_in[3];
    const float* b1    = (const float*)d_in[4];
    const float* W2    = (const float*)d_in[5];
    const float* b2    = (const float*)d_in[6];
    const float* Wc    = (const float*)d_in[7];
    const float* bc    = (const float*)d_in[8];
    float* out = (float*)d_out;

    const int N = in_sizes[0] / 128;
    const int E = in_sizes[1] / 2;
    const int NC = 10;
    const int G = out_size / (NC + 128);

    const int* src = ei;
    const int* dst = ei + E;

    const int EB   = 16384;
    const int NBLK = (E + EB - 1) / EB;
    const int NBUK = (N + 255) / 256;

    // workspace carve (256B aligned)
    char* wbase = (char*)d_ws;
    size_t off = 0;
    auto alloc = [&](size_t bytes) -> void* {
        void* p = wbase + off;
        off = (off + bytes + 255) & ~(size_t)255;
        return p;
    };
    float* dis     = (float*)alloc((size_t)N * 4);
    int*   row_ptr = (int*)alloc((size_t)(N + 1) * 4);
    int*   hist    = (int*)alloc((size_t)NBUK * NBLK * 4);
    int*   btot    = (int*)alloc((size_t)NBUK * 4);
    int*   bbase   = (int*)alloc((size_t)(NBUK + 1) * 4);
    unsigned int* coarse = (unsigned int*)alloc((size_t)E * 4);
    int*   col     = (int*)alloc((size_t)E * 4);
    unsigned short* bufT = (unsigned short*)alloc((size_t)N * 128 * 2);
    unsigned short* bufH = (unsigned short*)alloc((size_t)N * 128 * 2);

    // CSR build (no big global atomics, no memsets)
    hist_k<<<NBLK, 256, 0, stream>>>(dst, hist, E, NBUK, NBLK, EB);
    scanA_k<<<(NBUK * 64 + 255) / 256, 256, 0, stream>>>(hist, btot, NBUK, NBLK);
    scanB_k<<<1, 512, 0, stream>>>(btot, bbase, NBUK);
    scatter_k<<<NBLK, 256, 0, stream>>>(src, dst, hist, bbase, coarse, E, NBUK, NBLK, EB);
    bucket_k<<<NBUK, 256, 0, stream>>>(coarse, bbase, dis, row_ptr, col, N, NBUK, E);

    const int gemmBlocks = (N + 63) / 64;
    gemm_mfma_k<true><<<gemmBlocks, 256, 0, stream>>>(x, W1, dis, bufT, N);
    agg_k<<<(N + 3) / 4, 256, 0, stream>>>(bufT, bufH, row_ptr, col, dis, b1, N);
    gemm_mfma_k<false><<<gemmBlocks, 256, 0, stream>>>(bufH, W2, dis, bufT, N);
    agg_k<<<(N + 3) / 4, 256, 0, stream>>>(bufT, bufH, row_ptr, col, dis, b2, N);

    float* pooled = out + (size_t)G * NC;
    pool_logits_k<<<G, 128, 0, stream>>>(bufH, batch, Wc, bc, out, pooled, N, NC);
}

// Round 10
// 403.592 us; speedup vs baseline: 2.0458x; 1.0422x over previous
//
#include <hip/hip_runtime.h>
#include <hip/hip_bf16.h>

typedef short bf16x8 __attribute__((ext_vector_type(8)));
typedef float f32x4 __attribute__((ext_vector_type(4)));
typedef unsigned int u32x4 __attribute__((ext_vector_type(4)));

__device__ __forceinline__ unsigned short f2bf(float f) {
    unsigned int u = __float_as_uint(f);
    unsigned int r = u + 0x7fffu + ((u >> 16) & 1u);
    return (unsigned short)(r >> 16);
}
__device__ __forceinline__ float bf2f(unsigned short b) {
    return __uint_as_float(((unsigned int)b) << 16);
}
__device__ __forceinline__ unsigned int packbf2(float lo, float hi) {
    return ((unsigned int)f2bf(hi) << 16) | (unsigned int)f2bf(lo);
}

// ---------------- pass 1: per-block bucket histogram (bucket = dst>>8) + fused W1/W2 bf16-transpose prep ----------------
// blocks [0, nblk): histogram.  blocks [nblk, nblk+64): WT prep (WTg[n*128+k] = bf16(W[k*128+n])).
__global__ __launch_bounds__(256) void hist_k(const int* __restrict__ dst, int* __restrict__ hist,
                                              const float* __restrict__ W1, const float* __restrict__ W2,
                                              unsigned short* __restrict__ wt1, unsigned short* __restrict__ wt2,
                                              int e, int nbuk, int nblk, int eb) {
    int blk = blockIdx.x, t = threadIdx.x;
    if (blk >= nblk) {
        int j = (blk - nblk) * 256 + t;          // 0..16383
        int k = j >> 7, nn = j & 127;
        wt1[nn * 128 + k] = f2bf(W1[j]);
        wt2[nn * 128 + k] = f2bf(W2[j]);
        return;
    }
    __shared__ int lh[512];
    for (int j = t; j < nbuk; j += 256) lh[j] = 0;
    __syncthreads();
    int e0 = blk * eb, e1 = min(e, e0 + eb);
    for (int i = e0 + t; i < e1; i += 256) atomicAdd(&lh[dst[i] >> 8], 1);
    __syncthreads();
    for (int j = t; j < nbuk; j += 256) hist[(size_t)j * nblk + blk] = lh[j];
}

// ---------------- pass 2a: per-bucket exclusive scan over blocks; bucket totals ----------------
__global__ __launch_bounds__(256) void scanA_k(int* __restrict__ hist, int* __restrict__ btot, int nbuk, int nblk) {
    int w = (blockIdx.x * 256 + threadIdx.x) >> 6;
    int lane = threadIdx.x & 63;
    if (w >= nbuk) return;
    size_t base = (size_t)w * nblk;
    int run = 0;
    for (int c = 0; c < nblk; c += 64) {
        int i = c + lane;
        int v = (i < nblk) ? hist[base + i] : 0;
        int orig = v;
        for (int d = 1; d < 64; d <<= 1) { int u = __shfl_up(v, d); if (lane >= d) v += u; }
        if (i < nblk) hist[base + i] = run + v - orig;   // exclusive within bucket
        run += __shfl(v, 63);
    }
    if (lane == 0) btot[w] = run;
}

// ---------------- pass 2b: scan bucket totals -> bucket bases ----------------
__global__ __launch_bounds__(512) void scanB_k(const int* __restrict__ btot, int* __restrict__ bbase, int nbuk) {
    __shared__ int s[512];
    int t = threadIdx.x;
    int v = (t < nbuk) ? btot[t] : 0;
    s[t] = v;
    __syncthreads();
    for (int st = 1; st < 512; st <<= 1) {
        int add = (t >= st) ? s[t - st] : 0;
        __syncthreads();
        s[t] += add;
        __syncthreads();
    }
    if (t < nbuk) bbase[t] = s[t] - v;
    if (t == nbuk - 1) bbase[nbuk] = s[t];
}

// ---------------- pass 3: coarse scatter into bucket regions (packed dstlocal|src) ----------------
__global__ __launch_bounds__(256) void scatter_k(const int* __restrict__ src, const int* __restrict__ dst,
                                                 const int* __restrict__ hist, const int* __restrict__ bbase,
                                                 unsigned int* __restrict__ coarse, int e, int nbuk, int nblk, int eb) {
    __shared__ int cur[512];
    int blk = blockIdx.x, t = threadIdx.x;
    for (int j = t; j < nbuk; j += 256) cur[j] = bbase[j] + hist[(size_t)j * nblk + blk];
    __syncthreads();
    int e0 = blk * eb, e1 = min(e, e0 + eb);
    for (int i = e0 + t; i < e1; i += 256) {
        int s = src[i], d = dst[i];
        int bk = d >> 8;
        int p = atomicAdd(&cur[bk], 1);
        coarse[p] = ((unsigned int)(d & 255) << 24) | (unsigned int)s;
    }
}

// ---------------- pass 4: per-bucket fine sort -> row_ptr, col, dis ----------------
__global__ __launch_bounds__(256) void bucket_k(const unsigned int* __restrict__ coarse, const int* __restrict__ bbase,
                                                float* __restrict__ dis, int* __restrict__ row_ptr, int* __restrict__ col,
                                                int n, int nbuk, int e) {
    __shared__ int h[256];
    __shared__ int s[256];
    __shared__ int cur[256];
    int b = blockIdx.x, t = threadIdx.x;
    int e0 = bbase[b], e1 = bbase[b + 1];
    h[t] = 0;
    __syncthreads();
    for (int i = e0 + t; i < e1; i += 256) atomicAdd(&h[coarse[i] >> 24], 1);
    __syncthreads();
    int v = h[t];
    s[t] = v;
    __syncthreads();
    for (int st = 1; st < 256; st <<= 1) {
        int add = (t >= st) ? s[t - st] : 0;
        __syncthreads();
        s[t] += add;
        __syncthreads();
    }
    int excl = s[t] - v;
    int node = b * 256 + t;
    if (node < n) {
        row_ptr[node] = e0 + excl;
        dis[node] = rsqrtf((float)v + 1.0f);
    }
    cur[t] = e0 + excl;
    __syncthreads();
    for (int i = e0 + t; i < e1; i += 256) {
        unsigned int pk = coarse[i];
        int p = atomicAdd(&cur[pk >> 24], 1);
        col[p] = (int)(pk & 0x00FFFFFFu);
    }
    if (b == nbuk - 1 && t == 0) row_ptr[n] = e;
}

// ---------------- MFMA GEMM: C[r] = dis[r] * (A[r] @ W); A f32 (layer1) or bf16; C bf16 ----------------
// B comes pre-transposed/pre-converted: WTg[n*128+k] bf16. Staging = pure 32 KB copy.
template <bool INF32>
__global__ __launch_bounds__(256) void gemm_mfma_k(const void* __restrict__ Av, const unsigned short* __restrict__ WTg,
                                                   const float* __restrict__ dis, unsigned short* __restrict__ C,
                                                   int nrows) {
    __shared__ __align__(16) unsigned short WT[128 * 136];   // padded ld=136
    int t = threadIdx.x;
#pragma unroll
    for (int i = t; i < 2048; i += 256) {         // 2048 16B-chunks
        int nn = i >> 4, c = i & 15;
        *(u32x4*)&WT[nn * 136 + c * 8] = *(const u32x4*)&WTg[nn * 128 + c * 8];
    }
    __syncthreads();
    int wave = t >> 6, lane = t & 63;
    int lm = lane & 15, lg = lane >> 4;      // lg in 0..3
    for (int m0 = blockIdx.x * 64; m0 < nrows; m0 += gridDim.x * 64) {
        int R = m0 + wave * 16;
        int arow = R + lm;
        if (arow >= nrows) arow = nrows - 1;
        f32x4 acc[8];
#pragma unroll
        for (int q = 0; q < 8; q++) acc[q] = (f32x4){0.f, 0.f, 0.f, 0.f};
#pragma unroll
        for (int kk = 0; kk < 4; kk++) {
            bf16x8 af;
            if constexpr (INF32) {
                const float4* ap = (const float4*)((const float*)Av + (size_t)arow * 128 + kk * 32 + lg * 8);
                float4 a0 = ap[0], a1 = ap[1];
                u32x4 au;
                au[0] = packbf2(a0.x, a0.y); au[1] = packbf2(a0.z, a0.w);
                au[2] = packbf2(a1.x, a1.y); au[3] = packbf2(a1.z, a1.w);
                af = __builtin_bit_cast(bf16x8, au);
            } else {
                const u32x4* ap = (const u32x4*)((const unsigned short*)Av + (size_t)arow * 128);
                af = __builtin_bit_cast(bf16x8, ap[kk * 4 + lg]);
            }
#pragma unroll
            for (int q = 0; q < 8; q++) {
                const u32x4* bp = (const u32x4*)(WT + (q * 16 + lm) * 136 + kk * 32 + lg * 8);
                bf16x8 bfr = __builtin_bit_cast(bf16x8, *bp);          // B[k][n=q*16+lm]
                acc[q] = __builtin_amdgcn_mfma_f32_16x16x32_bf16(af, bfr, acc[q], 0, 0, 0);
            }
        }
        float dsc[4];
#pragma unroll
        for (int i2 = 0; i2 < 4; i2++) {
            int r = R + lg * 4 + i2;
            dsc[i2] = (r < nrows) ? dis[r] : 0.f;
        }
#pragma unroll
        for (int i2 = 0; i2 < 4; i2++) {
            int r = R + lg * 4 + i2;
            if (r < nrows) {
                unsigned short* cp = C + (size_t)r * 128 + lm;
#pragma unroll
                for (int q = 0; q < 8; q++) cp[q * 16] = f2bf(acc[q][i2] * dsc[i2]);
            }
        }
    }
}

// ---------------- aggregation: out[n] = relu(b + dis[n]*(h'[n] + sum h'[col[e]]))
// wave = 1 node; 4 edge-streams x 16 lanes; each lane gathers 16 B; 4-deep unroll per stream
__global__ __launch_bounds__(256, 8) void agg_k(const unsigned short* __restrict__ h, unsigned short* __restrict__ out,
                                                const int* __restrict__ row_ptr, const int* __restrict__ col,
                                                const float* __restrict__ dis, const float* __restrict__ bias, int n) {
    int wid  = (blockIdx.x * 256 + threadIdx.x) >> 6;
    int lane = threadIdx.x & 63;
    if (wid >= n) return;
    int g = lane >> 4;                 // edge stream 0..3
    int s = lane & 15;                 // 16B chunk within 256B row
    const char* hb = (const char*)h;
    unsigned int soff = (unsigned int)(s << 4);
    float acc0 = 0.f, acc1 = 0.f, acc2 = 0.f, acc3 = 0.f;
    float acc4 = 0.f, acc5 = 0.f, acc6 = 0.f, acc7 = 0.f;
#define ACCUM(v)                                                                              \
    acc0 += __uint_as_float((v)[0] << 16); acc1 += __uint_as_float((v)[0] & 0xffff0000u);     \
    acc2 += __uint_as_float((v)[1] << 16); acc3 += __uint_as_float((v)[1] & 0xffff0000u);     \
    acc4 += __uint_as_float((v)[2] << 16); acc5 += __uint_as_float((v)[2] & 0xffff0000u);     \
    acc6 += __uint_as_float((v)[3] << 16); acc7 += __uint_as_float((v)[3] & 0xffff0000u);
    if (g == 0) {   // self-loop row
        u32x4 v = *(const u32x4*)(hb + (((unsigned int)wid << 8) + soff));
        ACCUM(v)
    }
    int e = row_ptr[wid] + g, e1 = row_ptr[wid + 1];
    // main loop: 4 edges per stream in flight (16 rows / 4 KB per wave)
    for (; e + 12 < e1; e += 16) {
        int c0 = col[e], c1 = col[e + 4], c2 = col[e + 8], c3 = col[e + 12];
        u32x4 v0 = *(const u32x4*)(hb + (((unsigned int)c0 << 8) + soff));
        u32x4 v1 = *(const u32x4*)(hb + (((unsigned int)c1 << 8) + soff));
        u32x4 v2 = *(const u32x4*)(hb + (((unsigned int)c2 << 8) + soff));
        u32x4 v3 = *(const u32x4*)(hb + (((unsigned int)c3 << 8) + soff));
        ACCUM(v0)
        ACCUM(v1)
        ACCUM(v2)
        ACCUM(v3)
    }
    for (; e < e1; e += 4) {
        u32x4 v = *(const u32x4*)(hb + (((unsigned int)col[e] << 8) + soff));
        ACCUM(v)
    }
#undef ACCUM
    // combine the 4 edge-streams (lane bits 4,5)
#define RED(a) a += __shfl_xor(a, 16); a += __shfl_xor(a, 32);
    RED(acc0) RED(acc1) RED(acc2) RED(acc3) RED(acc4) RED(acc5) RED(acc6) RED(acc7)
#undef RED
    if (g == 0) {
        float d = dis[wid];
        const float4* bp = (const float4*)bias;
        float4 ba = bp[2 * s], bb = bp[2 * s + 1];
        u32x4 r;
        r[0] = packbf2(fmaxf(ba.x + d * acc0, 0.f), fmaxf(ba.y + d * acc1, 0.f));
        r[1] = packbf2(fmaxf(ba.z + d * acc2, 0.f), fmaxf(ba.w + d * acc3, 0.f));
        r[2] = packbf2(fmaxf(bb.x + d * acc4, 0.f), fmaxf(bb.y + d * acc5, 0.f));
        r[3] = packbf2(fmaxf(bb.z + d * acc6, 0.f), fmaxf(bb.w + d * acc7, 0.f));
        *(u32x4*)((char*)out + (((unsigned int)wid << 8) + soff)) = r;
    }
}

// ---------------- fused global mean pool + classifier ----------------
__global__ __launch_bounds__(128) void pool_logits_k(const unsigned short* __restrict__ h, const int* __restrict__ batch,
                                                     const float* __restrict__ Wc, const float* __restrict__ bc,
                                                     float* __restrict__ logits, float* __restrict__ pooled,
                                                     int n, int nc) {
    __shared__ float pl[128];
    int g = blockIdx.x;
    int j = threadIdx.x;
    int lo = 0, hi = n;
    while (lo < hi) { int mid = (lo + hi) >> 1; if (batch[mid] < g) lo = mid + 1; else hi = mid; }
    int start = lo;
    hi = n;
    while (lo < hi) { int mid = (lo + hi) >> 1; if (batch[mid] < g + 1) lo = mid + 1; else hi = mid; }
    int end = lo;
    float acc = 0.f;
    for (int r = start; r < end; r++) acc += bf2f(h[(size_t)r * 128 + j]);
    float pv = acc / fmaxf((float)(end - start), 1.0f);
    pooled[(size_t)g * 128 + j] = pv;
    pl[j] = pv;
    __syncthreads();
    if (j < nc) {
        float a = bc[j];
#pragma unroll 8
        for (int k = 0; k < 128; k++) a += pl[k] * Wc[k * nc + j];
        logits[(size_t)g * nc + j] = a;
    }
}

extern "C" void kernel_launch(void* const* d_in, const int* in_sizes, int n_in,
                              void* d_out, int out_size, void* d_ws, size_t ws_size,
                              hipStream_t stream) {
    const float* x     = (const float*)d_in[0];
    const int*   ei    = (const int*)d_in[1];
    const int*   batch = (const int*)d_in[2];
    const float* W1    = (const float*)d_in[3];
    const float* b1    = (const float*)d_in[4];
    const float* W2    = (const float*)d_in[5];
    const float* b2    = (const float*)d_in[6];
    const float* Wc    = (const float*)d_in[7];
    const float* bc    = (const float*)d_in[8];
    float* out = (float*)d_out;

    const int N = in_sizes[0] / 128;
    const int E = in_sizes[1] / 2;
    const int NC = 10;
    const int G = out_size / (NC + 128);

    const int* src = ei;
    const int* dst = ei + E;

    const int EB   = 8192;
    const int NBLK = (E + EB - 1) / EB;
    const int NBUK = (N + 255) / 256;

    // workspace carve (256B aligned)
    char* wbase = (char*)d_ws;
    size_t off = 0;
    auto alloc = [&](size_t bytes) -> void* {
        void* p = wbase + off;
        off = (off + bytes + 255) & ~(size_t)255;
        return p;
    };
    float* dis     = (float*)alloc((size_t)N * 4);
    int*   row_ptr = (int*)alloc((size_t)(N + 1) * 4);
    int*   hist    = (int*)alloc((size_t)NBUK * NBLK * 4);
    int*   btot    = (int*)alloc((size_t)NBUK * 4);
    int*   bbase   = (int*)alloc((size_t)(NBUK + 1) * 4);
    unsigned int* coarse = (unsigned int*)alloc((size_t)E * 4);
    int*   col     = (int*)alloc((size_t)E * 4);
    unsigned short* wt1 = (unsigned short*)alloc((size_t)128 * 128 * 2);
    unsigned short* wt2 = (unsigned short*)alloc((size_t)128 * 128 * 2);
    unsigned short* bufT = (unsigned short*)alloc((size_t)N * 128 * 2);
    unsigned short* bufH = (unsigned short*)alloc((size_t)N * 128 * 2);

    // CSR build (+fused W-prep blocks on the first launch)
    hist_k<<<NBLK + 64, 256, 0, stream>>>(dst, hist, W1, W2, wt1, wt2, E, NBUK, NBLK, EB);
    scanA_k<<<(NBUK * 64 + 255) / 256, 256, 0, stream>>>(hist, btot, NBUK, NBLK);
    scanB_k<<<1, 512, 0, stream>>>(btot, bbase, NBUK);
    scatter_k<<<NBLK, 256, 0, stream>>>(src, dst, hist, bbase, coarse, E, NBUK, NBLK, EB);
    bucket_k<<<NBUK, 256, 0, stream>>>(coarse, bbase, dis, row_ptr, col, N, NBUK, E);

    const int gemmBlocks = (N + 63) / 64;
    gemm_mfma_k<true><<<gemmBlocks, 256, 0, stream>>>(x, wt1, dis, bufT, N);
    agg_k<<<(N + 3) / 4, 256, 0, stream>>>(bufT, bufH, row_ptr, col, dis, b1, N);
    gemm_mfma_k<false><<<gemmBlocks, 256, 0, stream>>>(bufH, wt2, dis, bufT, N);
    agg_k<<<(N + 3) / 4, 256, 0, stream>>>(bufT, bufH, row_ptr, col, dis, b2, N);

    float* pooled = out + (size_t)G * NC;
    pool_logits_k<<<G, 128, 0, stream>>>(bufH, batch, Wc, bc, out, pooled, N, NC);
}

// Round 11
// 395.571 us; speedup vs baseline: 2.0872x; 1.0203x over previous
//
#include <hip/hip_runtime.h>
#include <hip/hip_bf16.h>

typedef short bf16x8 __attribute__((ext_vector_type(8)));
typedef float f32x4 __attribute__((ext_vector_type(4)));
typedef unsigned int u32x4 __attribute__((ext_vector_type(4)));

__device__ __forceinline__ unsigned short f2bf(float f) {
    unsigned int u = __float_as_uint(f);
    unsigned int r = u + 0x7fffu + ((u >> 16) & 1u);
    return (unsigned short)(r >> 16);
}
__device__ __forceinline__ float bf2f(unsigned short b) {
    return __uint_as_float(((unsigned int)b) << 16);
}
__device__ __forceinline__ unsigned int packbf2(float lo, float hi) {
    return ((unsigned int)f2bf(hi) << 16) | (unsigned int)f2bf(lo);
}

// ---------------- fused launch 1: hist (blocks [0,nblk)) + wt2 prep ([nblk,nblk+64)) + gemm1 (rest) ----------------
// gemm1: T[r] = (x @ W1)[r], UNSCALED (dis not available yet); f2bf staging of W1 into LDS.
__global__ __launch_bounds__(256) void build1_k(const int* __restrict__ dst, int* __restrict__ hist,
                                                const float* __restrict__ W1, const float* __restrict__ W2,
                                                unsigned short* __restrict__ wt2,
                                                const float* __restrict__ x, unsigned short* __restrict__ T,
                                                int nrows, int e, int nbuk, int nblk, int eb, int g1) {
    __shared__ int lh[512];
    __shared__ __align__(16) unsigned short WT[128 * 136];
    int blk = blockIdx.x, t = threadIdx.x;
    if (blk < nblk) {
        // ---- histogram over dst buckets, int4 reads ----
        for (int j = t; j < nbuk; j += 256) lh[j] = 0;
        __syncthreads();
        int e0 = blk * eb, e1 = min(e, e0 + eb);
        int L = e1 - e0;
        int i = e0 + t * 4;
        for (; i + 3 < e1; i += 1024) {
            int4 d4 = *(const int4*)(dst + i);
            atomicAdd(&lh[d4.x >> 8], 1);
            atomicAdd(&lh[d4.y >> 8], 1);
            atomicAdd(&lh[d4.z >> 8], 1);
            atomicAdd(&lh[d4.w >> 8], 1);
        }
        int rem = L & 3;
        if (t < rem) atomicAdd(&lh[dst[e1 - rem + t] >> 8], 1);
        __syncthreads();
        for (int j = t; j < nbuk; j += 256) hist[(size_t)j * nblk + blk] = lh[j];
    } else if (blk < nblk + 64) {
        // ---- wt2 prep: wt2[n*128+k] = bf16(W2[k*128+n]) ----
        int j = (blk - nblk) * 256 + t;
        int k = j >> 7, nn = j & 127;
        wt2[nn * 128 + k] = f2bf(W2[j]);
    } else {
        // ---- gemm1 (unscaled) ----
        int bid = blk - nblk - 64;
        for (int i = t; i < 16384; i += 256) {
            int k = i >> 7, nn = i & 127;
            WT[nn * 136 + k] = f2bf(W1[i]);
        }
        __syncthreads();
        int wave = t >> 6, lane = t & 63;
        int lm = lane & 15, lg = lane >> 4;
        for (int m0 = bid * 64; m0 < nrows; m0 += g1 * 64) {
            int R = m0 + wave * 16;
            int arow = R + lm;
            if (arow >= nrows) arow = nrows - 1;
            f32x4 acc[8];
#pragma unroll
            for (int q = 0; q < 8; q++) acc[q] = (f32x4){0.f, 0.f, 0.f, 0.f};
#pragma unroll
            for (int kk = 0; kk < 4; kk++) {
                const float4* ap = (const float4*)(x + (size_t)arow * 128 + kk * 32 + lg * 8);
                float4 a0 = ap[0], a1 = ap[1];
                u32x4 au;
                au[0] = packbf2(a0.x, a0.y); au[1] = packbf2(a0.z, a0.w);
                au[2] = packbf2(a1.x, a1.y); au[3] = packbf2(a1.z, a1.w);
                bf16x8 af = __builtin_bit_cast(bf16x8, au);
#pragma unroll
                for (int q = 0; q < 8; q++) {
                    const u32x4* bp = (const u32x4*)(WT + (q * 16 + lm) * 136 + kk * 32 + lg * 8);
                    bf16x8 bfr = __builtin_bit_cast(bf16x8, *bp);
                    acc[q] = __builtin_amdgcn_mfma_f32_16x16x32_bf16(af, bfr, acc[q], 0, 0, 0);
                }
            }
#pragma unroll
            for (int i2 = 0; i2 < 4; i2++) {
                int r = R + lg * 4 + i2;
                if (r < nrows) {
                    unsigned short* cp = T + (size_t)r * 128 + lm;
#pragma unroll
                    for (int q = 0; q < 8; q++) cp[q * 16] = f2bf(acc[q][i2]);
                }
            }
        }
    }
}

// ---------------- per-bucket exclusive scan over blocks (in-place) + bucket totals ----------------
__global__ __launch_bounds__(256) void scanA_k(int* __restrict__ hist, int* __restrict__ btot, int nbuk, int nblk) {
    int w = (blockIdx.x * 256 + threadIdx.x) >> 6;
    int lane = threadIdx.x & 63;
    if (w >= nbuk) return;
    size_t base = (size_t)w * nblk;
    int run = 0;
    for (int c = 0; c < nblk; c += 64) {
        int i = c + lane;
        int v = (i < nblk) ? hist[base + i] : 0;
        int orig = v;
        for (int d = 1; d < 64; d <<= 1) { int u = __shfl_up(v, d); if (lane >= d) v += u; }
        if (i < nblk) hist[base + i] = run + v - orig;   // exclusive within bucket
        run += __shfl(v, 63);
    }
    if (lane == 0) btot[w] = run;
}

// ---------------- coarse scatter; bucket bases self-computed from btot (wave-0 shfl scan) ----------------
__global__ __launch_bounds__(256) void scatter_k(const int* __restrict__ src, const int* __restrict__ dst,
                                                 const int* __restrict__ hist, const int* __restrict__ btot,
                                                 unsigned int* __restrict__ coarse, int e, int nbuk, int nblk, int eb) {
    __shared__ int lbase[512];
    __shared__ int cur[512];
    int blk = blockIdx.x, t = threadIdx.x;
    int wv = t >> 6, lane = t & 63;
    if (wv == 0) {
        int run = 0;
        for (int c = 0; c < nbuk; c += 64) {
            int i = c + lane;
            int v = (i < nbuk) ? btot[i] : 0;
            int orig = v;
            for (int d = 1; d < 64; d <<= 1) { int u = __shfl_up(v, d); if (lane >= d) v += u; }
            if (i < nbuk) lbase[i] = run + v - orig;
            run += __shfl(v, 63);
        }
    }
    __syncthreads();
    for (int j = t; j < nbuk; j += 256) cur[j] = lbase[j] + hist[(size_t)j * nblk + blk];
    __syncthreads();
    int e0 = blk * eb, e1 = min(e, e0 + eb);
    int L = e1 - e0;
    int i = e0 + t * 4;
    for (; i + 3 < e1; i += 1024) {
        int4 s4 = *(const int4*)(src + i);
        int4 d4 = *(const int4*)(dst + i);
        int p0 = atomicAdd(&cur[d4.x >> 8], 1);
        coarse[p0] = ((unsigned int)(d4.x & 255) << 24) | (unsigned int)s4.x;
        int p1 = atomicAdd(&cur[d4.y >> 8], 1);
        coarse[p1] = ((unsigned int)(d4.y & 255) << 24) | (unsigned int)s4.y;
        int p2 = atomicAdd(&cur[d4.z >> 8], 1);
        coarse[p2] = ((unsigned int)(d4.z & 255) << 24) | (unsigned int)s4.z;
        int p3 = atomicAdd(&cur[d4.w >> 8], 1);
        coarse[p3] = ((unsigned int)(d4.w & 255) << 24) | (unsigned int)s4.w;
    }
    int rem = L & 3;
    if (t < rem) {
        int idx = e1 - rem + t;
        int s = src[idx], d = dst[idx];
        int p = atomicAdd(&cur[d >> 8], 1);
        coarse[p] = ((unsigned int)(d & 255) << 24) | (unsigned int)s;
    }
}

// ---------------- per-bucket fine sort -> row_ptr, col, dis; bases self-computed ----------------
__global__ __launch_bounds__(256) void bucket_k(const unsigned int* __restrict__ coarse, const int* __restrict__ btot,
                                                float* __restrict__ dis, int* __restrict__ row_ptr, int* __restrict__ col,
                                                int n, int nbuk, int e) {
    __shared__ int lbase[512];
    __shared__ int h[256];
    __shared__ int s[256];
    __shared__ int cur[256];
    int b = blockIdx.x, t = threadIdx.x;
    int wv = t >> 6, lane = t & 63;
    if (wv == 0) {
        int run = 0;
        for (int c = 0; c < nbuk; c += 64) {
            int i = c + lane;
            int v = (i < nbuk) ? btot[i] : 0;
            int orig = v;
            for (int d = 1; d < 64; d <<= 1) { int u = __shfl_up(v, d); if (lane >= d) v += u; }
            if (i < nbuk) lbase[i] = run + v - orig;
            run += __shfl(v, 63);
        }
        if (lane == 0) lbase[nbuk] = run;
    }
    h[t] = 0;
    __syncthreads();
    int e0 = lbase[b], e1 = lbase[b + 1];
    for (int i = e0 + t; i < e1; i += 256) atomicAdd(&h[coarse[i] >> 24], 1);
    __syncthreads();
    int v = h[t];
    s[t] = v;
    __syncthreads();
    for (int st = 1; st < 256; st <<= 1) {
        int add = (t >= st) ? s[t - st] : 0;
        __syncthreads();
        s[t] += add;
        __syncthreads();
    }
    int excl = s[t] - v;
    int node = b * 256 + t;
    if (node < n) {
        row_ptr[node] = e0 + excl;
        dis[node] = rsqrtf((float)v + 1.0f);
    }
    cur[t] = e0 + excl;
    __syncthreads();
    for (int i = e0 + t; i < e1; i += 256) {
        unsigned int pk = coarse[i];
        int p = atomicAdd(&cur[pk >> 24], 1);
        col[p] = (int)(pk & 0x00FFFFFFu);
    }
    if (b == nbuk - 1 && t == 0) row_ptr[n] = e;
}

// ---------------- MFMA GEMM (layer 2): C[r] = dis[r] * (A[r] @ W); A bf16; WTg pre-converted ----------------
template <bool INF32>
__global__ __launch_bounds__(256) void gemm_mfma_k(const void* __restrict__ Av, const unsigned short* __restrict__ WTg,
                                                   const float* __restrict__ dis, unsigned short* __restrict__ C,
                                                   int nrows) {
    __shared__ __align__(16) unsigned short WT[128 * 136];
    int t = threadIdx.x;
#pragma unroll
    for (int i = t; i < 2048; i += 256) {
        int nn = i >> 4, c = i & 15;
        *(u32x4*)&WT[nn * 136 + c * 8] = *(const u32x4*)&WTg[nn * 128 + c * 8];
    }
    __syncthreads();
    int wave = t >> 6, lane = t & 63;
    int lm = lane & 15, lg = lane >> 4;
    for (int m0 = blockIdx.x * 64; m0 < nrows; m0 += gridDim.x * 64) {
        int R = m0 + wave * 16;
        int arow = R + lm;
        if (arow >= nrows) arow = nrows - 1;
        f32x4 acc[8];
#pragma unroll
        for (int q = 0; q < 8; q++) acc[q] = (f32x4){0.f, 0.f, 0.f, 0.f};
#pragma unroll
        for (int kk = 0; kk < 4; kk++) {
            bf16x8 af;
            if constexpr (INF32) {
                const float4* ap = (const float4*)((const float*)Av + (size_t)arow * 128 + kk * 32 + lg * 8);
                float4 a0 = ap[0], a1 = ap[1];
                u32x4 au;
                au[0] = packbf2(a0.x, a0.y); au[1] = packbf2(a0.z, a0.w);
                au[2] = packbf2(a1.x, a1.y); au[3] = packbf2(a1.z, a1.w);
                af = __builtin_bit_cast(bf16x8, au);
            } else {
                const u32x4* ap = (const u32x4*)((const unsigned short*)Av + (size_t)arow * 128);
                af = __builtin_bit_cast(bf16x8, ap[kk * 4 + lg]);
            }
#pragma unroll
            for (int q = 0; q < 8; q++) {
                const u32x4* bp = (const u32x4*)(WT + (q * 16 + lm) * 136 + kk * 32 + lg * 8);
                bf16x8 bfr = __builtin_bit_cast(bf16x8, *bp);
                acc[q] = __builtin_amdgcn_mfma_f32_16x16x32_bf16(af, bfr, acc[q], 0, 0, 0);
            }
        }
        float dsc[4];
#pragma unroll
        for (int i2 = 0; i2 < 4; i2++) {
            int r = R + lg * 4 + i2;
            dsc[i2] = (r < nrows) ? dis[r] : 0.f;
        }
#pragma unroll
        for (int i2 = 0; i2 < 4; i2++) {
            int r = R + lg * 4 + i2;
            if (r < nrows) {
                unsigned short* cp = C + (size_t)r * 128 + lm;
#pragma unroll
                for (int q = 0; q < 8; q++) cp[q * 16] = f2bf(acc[q][i2] * dsc[i2]);
            }
        }
    }
}

// ---------------- aggregation ----------------
// EDGE_DIS=true  (layer1, h=T unscaled): out = relu(b + dis[n]*(dis[n]*T[n] + sum dis[c]*T[c]))
// EDGE_DIS=false (layer2, h pre-scaled): out = relu(b + dis[n]*(h[n] + sum h[c]))
template <bool EDGE_DIS>
__global__ __launch_bounds__(256, 8) void agg_k(const unsigned short* __restrict__ h, unsigned short* __restrict__ out,
                                                const int* __restrict__ row_ptr, const int* __restrict__ col,
                                                const float* __restrict__ dis, const float* __restrict__ bias, int n) {
    int wid  = (blockIdx.x * 256 + threadIdx.x) >> 6;
    int lane = threadIdx.x & 63;
    if (wid >= n) return;
    int g = lane >> 4;                 // edge stream 0..3
    int s = lane & 15;                 // 16B chunk within 256B row
    const char* hb = (const char*)h;
    unsigned int soff = (unsigned int)(s << 4);
    float dn = dis[wid];
    float acc0 = 0.f, acc1 = 0.f, acc2 = 0.f, acc3 = 0.f;
    float acc4 = 0.f, acc5 = 0.f, acc6 = 0.f, acc7 = 0.f;
#define ACCUMW(v, w)                                                                                  \
    acc0 += (w) * __uint_as_float((v)[0] << 16); acc1 += (w) * __uint_as_float((v)[0] & 0xffff0000u); \
    acc2 += (w) * __uint_as_float((v)[1] << 16); acc3 += (w) * __uint_as_float((v)[1] & 0xffff0000u); \
    acc4 += (w) * __uint_as_float((v)[2] << 16); acc5 += (w) * __uint_as_float((v)[2] & 0xffff0000u); \
    acc6 += (w) * __uint_as_float((v)[3] << 16); acc7 += (w) * __uint_as_float((v)[3] & 0xffff0000u);
    if (g == 0) {   // self-loop row
        u32x4 v = *(const u32x4*)(hb + (((unsigned int)wid << 8) + soff));
        float w = EDGE_DIS ? dn : 1.0f;
        ACCUMW(v, w)
    }
    int e = row_ptr[wid] + g, e1 = row_ptr[wid + 1];
    for (; e + 12 < e1; e += 16) {
        int c0 = col[e], c1 = col[e + 4], c2 = col[e + 8], c3 = col[e + 12];
        float w0 = 1.f, w1 = 1.f, w2 = 1.f, w3 = 1.f;
        if constexpr (EDGE_DIS) { w0 = dis[c0]; w1 = dis[c1]; w2 = dis[c2]; w3 = dis[c3]; }
        u32x4 v0 = *(const u32x4*)(hb + (((unsigned int)c0 << 8) + soff));
        u32x4 v1 = *(const u32x4*)(hb + (((unsigned int)c1 << 8) + soff));
        u32x4 v2 = *(const u32x4*)(hb + (((unsigned int)c2 << 8) + soff));
        u32x4 v3 = *(const u32x4*)(hb + (((unsigned int)c3 << 8) + soff));
        ACCUMW(v0, w0)
        ACCUMW(v1, w1)
        ACCUMW(v2, w2)
        ACCUMW(v3, w3)
    }
    for (; e < e1; e += 4) {
        int c = col[e];
        float w = 1.f;
        if constexpr (EDGE_DIS) w = dis[c];
        u32x4 v = *(const u32x4*)(hb + (((unsigned int)c << 8) + soff));
        ACCUMW(v, w)
    }
#undef ACCUMW
#define RED(a) a += __shfl_xor(a, 16); a += __shfl_xor(a, 32);
    RED(acc0) RED(acc1) RED(acc2) RED(acc3) RED(acc4) RED(acc5) RED(acc6) RED(acc7)
#undef RED
    if (g == 0) {
        const float4* bp = (const float4*)bias;
        float4 ba = bp[2 * s], bb = bp[2 * s + 1];
        u32x4 r;
        r[0] = packbf2(fmaxf(ba.x + dn * acc0, 0.f), fmaxf(ba.y + dn * acc1, 0.f));
        r[1] = packbf2(fmaxf(ba.z + dn * acc2, 0.f), fmaxf(ba.w + dn * acc3, 0.f));
        r[2] = packbf2(fmaxf(bb.x + dn * acc4, 0.f), fmaxf(bb.y + dn * acc5, 0.f));
        r[3] = packbf2(fmaxf(bb.z + dn * acc6, 0.f), fmaxf(bb.w + dn * acc7, 0.f));
        *(u32x4*)((char*)out + (((unsigned int)wid << 8) + soff)) = r;
    }
}

// ---------------- fused global mean pool + classifier ----------------
__global__ __launch_bounds__(128) void pool_logits_k(const unsigned short* __restrict__ h, const int* __restrict__ batch,
                                                     const float* __restrict__ Wc, const float* __restrict__ bc,
                                                     float* __restrict__ logits, float* __restrict__ pooled,
                                                     int n, int nc) {
    __shared__ float pl[128];
    int g = blockIdx.x;
    int j = threadIdx.x;
    int lo = 0, hi = n;
    while (lo < hi) { int mid = (lo + hi) >> 1; if (batch[mid] < g) lo = mid + 1; else hi = mid; }
    int start = lo;
    hi = n;
    while (lo < hi) { int mid = (lo + hi) >> 1; if (batch[mid] < g + 1) lo = mid + 1; else hi = mid; }
    int end = lo;
    float acc = 0.f;
    for (int r = start; r < end; r++) acc += bf2f(h[(size_t)r * 128 + j]);
    float pv = acc / fmaxf((float)(end - start), 1.0f);
    pooled[(size_t)g * 128 + j] = pv;
    pl[j] = pv;
    __syncthreads();
    if (j < nc) {
        float a = bc[j];
#pragma unroll 8
        for (int k = 0; k < 128; k++) a += pl[k] * Wc[k * nc + j];
        logits[(size_t)g * nc + j] = a;
    }
}

extern "C" void kernel_launch(void* const* d_in, const int* in_sizes, int n_in,
                              void* d_out, int out_size, void* d_ws, size_t ws_size,
                              hipStream_t stream) {
    const float* x     = (const float*)d_in[0];
    const int*   ei    = (const int*)d_in[1];
    const int*   batch = (const int*)d_in[2];
    const float* W1    = (const float*)d_in[3];
    const float* b1    = (const float*)d_in[4];
    const float* W2    = (const float*)d_in[5];
    const float* b2    = (const float*)d_in[6];
    const float* Wc    = (const float*)d_in[7];
    const float* bc    = (const float*)d_in[8];
    float* out = (float*)d_out;

    const int N = in_sizes[0] / 128;
    const int E = in_sizes[1] / 2;
    const int NC = 10;
    const int G = out_size / (NC + 128);

    const int* src = ei;
    const int* dst = ei + E;

    const int EB   = 8192;
    const int NBLK = (E + EB - 1) / EB;
    const int NBUK = (N + 255) / 256;

    // workspace carve (256B aligned)
    char* wbase = (char*)d_ws;
    size_t off = 0;
    auto alloc = [&](size_t bytes) -> void* {
        void* p = wbase + off;
        off = (off + bytes + 255) & ~(size_t)255;
        return p;
    };
    float* dis     = (float*)alloc((size_t)N * 4);
    int*   row_ptr = (int*)alloc((size_t)(N + 1) * 4);
    int*   hist    = (int*)alloc((size_t)NBUK * NBLK * 4);
    int*   btot    = (int*)alloc((size_t)NBUK * 4);
    unsigned int* coarse = (unsigned int*)alloc((size_t)E * 4);
    int*   col     = (int*)alloc((size_t)E * 4);
    unsigned short* wt2 = (unsigned short*)alloc((size_t)128 * 128 * 2);
    unsigned short* bufT = (unsigned short*)alloc((size_t)N * 128 * 2);
    unsigned short* bufH = (unsigned short*)alloc((size_t)N * 128 * 2);

    // fused: hist + wt2-prep + gemm1 (unscaled T = x@W1)
    const int G1 = 782;   // gemm1 sub-grid (2 tiles per block)
    build1_k<<<NBLK + 64 + G1, 256, 0, stream>>>(dst, hist, W1, W2, wt2, x, bufT, N, E, NBUK, NBLK, EB, G1);
    scanA_k<<<(NBUK * 64 + 255) / 256, 256, 0, stream>>>(hist, btot, NBUK, NBLK);
    scatter_k<<<NBLK, 256, 0, stream>>>(src, dst, hist, btot, coarse, E, NBUK, NBLK, EB);
    bucket_k<<<NBUK, 256, 0, stream>>>(coarse, btot, dis, row_ptr, col, N, NBUK, E);

    agg_k<true><<<(N + 3) / 4, 256, 0, stream>>>(bufT, bufH, row_ptr, col, dis, b1, N);
    gemm_mfma_k<false><<<(N + 63) / 64, 256, 0, stream>>>(bufH, wt2, dis, bufT, N);
    agg_k<false><<<(N + 3) / 4, 256, 0, stream>>>(bufT, bufH, row_ptr, col, dis, b2, N);

    float* pooled = out + (size_t)G * NC;
    pool_logits_k<<<G, 128, 0, stream>>>(bufH, batch, Wc, bc, out, pooled, N, NC);
}

// Round 12
// 391.957 us; speedup vs baseline: 2.1065x; 1.0092x over previous
//
#include <hip/hip_runtime.h>
#include <hip/hip_bf16.h>

typedef short bf16x8 __attribute__((ext_vector_type(8)));
typedef float f32x4 __attribute__((ext_vector_type(4)));
typedef unsigned int u32x4 __attribute__((ext_vector_type(4)));

__device__ __forceinline__ unsigned short f2bf(float f) {
    unsigned int u = __float_as_uint(f);
    unsigned int r = u + 0x7fffu + ((u >> 16) & 1u);
    return (unsigned short)(r >> 16);
}
__device__ __forceinline__ float bf2f(unsigned short b) {
    return __uint_as_float(((unsigned int)b) << 16);
}
__device__ __forceinline__ unsigned int packbf2(float lo, float hi) {
    return ((unsigned int)f2bf(hi) << 16) | (unsigned int)f2bf(lo);
}

// ---------------- prep: wt[n*128+k] = bf16(W[k*128+n]) for W1, W2 ----------------
__global__ __launch_bounds__(256) void prep_k(const float* __restrict__ W1, const float* __restrict__ W2,
                                              unsigned short* __restrict__ wt1, unsigned short* __restrict__ wt2) {
    int j = blockIdx.x * 256 + threadIdx.x;    // 0..16383
    int k = j >> 7, nn = j & 127;
    wt1[nn * 128 + k] = f2bf(W1[j]);
    wt2[nn * 128 + k] = f2bf(W2[j]);
}

// ---------------- fused launch: hist (blocks [0,nblk)) + gemm1 (rest; unscaled T = x@W1) ----------------
__global__ __launch_bounds__(256) void build1_k(const int* __restrict__ dst, int* __restrict__ hist,
                                                const unsigned short* __restrict__ wt1,
                                                const float* __restrict__ x, unsigned short* __restrict__ T,
                                                int nrows, int e, int nbuk, int nblk, int eb, int g1) {
    __shared__ int lh[512];
    __shared__ __align__(16) unsigned short WT[128 * 136];
    int blk = blockIdx.x, t = threadIdx.x;
    if (blk < nblk) {
        // ---- histogram over dst buckets, int4 reads ----
        for (int j = t; j < nbuk; j += 256) lh[j] = 0;
        __syncthreads();
        int e0 = blk * eb, e1 = min(e, e0 + eb);
        int L = e1 - e0;
        int i = e0 + t * 4;
        for (; i + 3 < e1; i += 1024) {
            int4 d4 = *(const int4*)(dst + i);
            atomicAdd(&lh[d4.x >> 8], 1);
            atomicAdd(&lh[d4.y >> 8], 1);
            atomicAdd(&lh[d4.z >> 8], 1);
            atomicAdd(&lh[d4.w >> 8], 1);
        }
        int rem = L & 3;
        if (t < rem) atomicAdd(&lh[dst[e1 - rem + t] >> 8], 1);
        __syncthreads();
        for (int j = t; j < nbuk; j += 256) hist[(size_t)j * nblk + blk] = lh[j];
    } else {
        // ---- gemm1 (unscaled), pure-copy staging from wt1 ----
        int bid = blk - nblk;
#pragma unroll
        for (int i = t; i < 2048; i += 256) {
            int nn = i >> 4, c = i & 15;
            *(u32x4*)&WT[nn * 136 + c * 8] = *(const u32x4*)&wt1[nn * 128 + c * 8];
        }
        __syncthreads();
        int wave = t >> 6, lane = t & 63;
        int lm = lane & 15, lg = lane >> 4;
        for (int m0 = bid * 64; m0 < nrows; m0 += g1 * 64) {
            int R = m0 + wave * 16;
            int arow = R + lm;
            if (arow >= nrows) arow = nrows - 1;
            f32x4 acc[8];
#pragma unroll
            for (int q = 0; q < 8; q++) acc[q] = (f32x4){0.f, 0.f, 0.f, 0.f};
#pragma unroll
            for (int kk = 0; kk < 4; kk++) {
                const float4* ap = (const float4*)(x + (size_t)arow * 128 + kk * 32 + lg * 8);
                float4 a0 = ap[0], a1 = ap[1];
                u32x4 au;
                au[0] = packbf2(a0.x, a0.y); au[1] = packbf2(a0.z, a0.w);
                au[2] = packbf2(a1.x, a1.y); au[3] = packbf2(a1.z, a1.w);
                bf16x8 af = __builtin_bit_cast(bf16x8, au);
#pragma unroll
                for (int q = 0; q < 8; q++) {
                    const u32x4* bp = (const u32x4*)(WT + (q * 16 + lm) * 136 + kk * 32 + lg * 8);
                    bf16x8 bfr = __builtin_bit_cast(bf16x8, *bp);
                    acc[q] = __builtin_amdgcn_mfma_f32_16x16x32_bf16(af, bfr, acc[q], 0, 0, 0);
                }
            }
#pragma unroll
            for (int i2 = 0; i2 < 4; i2++) {
                int r = R + lg * 4 + i2;
                if (r < nrows) {
                    unsigned short* cp = T + (size_t)r * 128 + lm;
#pragma unroll
                    for (int q = 0; q < 8; q++) cp[q * 16] = f2bf(acc[q][i2]);
                }
            }
        }
    }
}

// ---------------- per-bucket exclusive scan over blocks (in-place) + bucket totals ----------------
__global__ __launch_bounds__(256) void scanA_k(int* __restrict__ hist, int* __restrict__ btot, int nbuk, int nblk) {
    int w = (blockIdx.x * 256 + threadIdx.x) >> 6;
    int lane = threadIdx.x & 63;
    if (w >= nbuk) return;
    size_t base = (size_t)w * nblk;
    int run = 0;
    for (int c = 0; c < nblk; c += 64) {
        int i = c + lane;
        int v = (i < nblk) ? hist[base + i] : 0;
        int orig = v;
        for (int d = 1; d < 64; d <<= 1) { int u = __shfl_up(v, d); if (lane >= d) v += u; }
        if (i < nblk) hist[base + i] = run + v - orig;   // exclusive within bucket
        run += __shfl(v, 63);
    }
    if (lane == 0) btot[w] = run;
}

// ---------------- coarse scatter (512 thr); bucket bases self-computed from btot ----------------
__global__ __launch_bounds__(512) void scatter_k(const int* __restrict__ src, const int* __restrict__ dst,
                                                 const int* __restrict__ hist, const int* __restrict__ btot,
                                                 unsigned int* __restrict__ coarse, int e, int nbuk, int nblk, int eb) {
    __shared__ int lbase[512];
    __shared__ int cur[512];
    int blk = blockIdx.x, t = threadIdx.x;
    int wv = t >> 6, lane = t & 63;
    if (wv == 0) {
        int run = 0;
        for (int c = 0; c < nbuk; c += 64) {
            int i = c + lane;
            int v = (i < nbuk) ? btot[i] : 0;
            int orig = v;
            for (int d = 1; d < 64; d <<= 1) { int u = __shfl_up(v, d); if (lane >= d) v += u; }
            if (i < nbuk) lbase[i] = run + v - orig;
            run += __shfl(v, 63);
        }
    }
    __syncthreads();
    for (int j = t; j < nbuk; j += 512) cur[j] = lbase[j] + hist[(size_t)j * nblk + blk];
    __syncthreads();
    int e0 = blk * eb, e1 = min(e, e0 + eb);
    int L = e1 - e0;
    int i = e0 + t * 4;
    for (; i + 3 < e1; i += 2048) {
        int4 s4 = *(const int4*)(src + i);
        int4 d4 = *(const int4*)(dst + i);
        int p0 = atomicAdd(&cur[d4.x >> 8], 1);
        coarse[p0] = ((unsigned int)(d4.x & 255) << 24) | (unsigned int)s4.x;
        int p1 = atomicAdd(&cur[d4.y >> 8], 1);
        coarse[p1] = ((unsigned int)(d4.y & 255) << 24) | (unsigned int)s4.y;
        int p2 = atomicAdd(&cur[d4.z >> 8], 1);
        coarse[p2] = ((unsigned int)(d4.z & 255) << 24) | (unsigned int)s4.z;
        int p3 = atomicAdd(&cur[d4.w >> 8], 1);
        coarse[p3] = ((unsigned int)(d4.w & 255) << 24) | (unsigned int)s4.w;
    }
    int rem = L & 3;
    if (t < rem) {
        int idx = e1 - rem + t;
        int s = src[idx], d = dst[idx];
        int p = atomicAdd(&cur[d >> 8], 1);
        coarse[p] = ((unsigned int)(d & 255) << 24) | (unsigned int)s;
    }
}

// ---------------- per-bucket fine sort (512 thr) -> row_ptr, col, dis; bases self-computed ----------------
__global__ __launch_bounds__(512) void bucket_k(const unsigned int* __restrict__ coarse, const int* __restrict__ btot,
                                                float* __restrict__ dis, int* __restrict__ row_ptr, int* __restrict__ col,
                                                int n, int nbuk, int e) {
    __shared__ int lbase[512];
    __shared__ int h[256];
    __shared__ int s[256];
    __shared__ int cur[256];
    int b = blockIdx.x, t = threadIdx.x;
    int wv = t >> 6, lane = t & 63;
    if (wv == 0) {
        int run = 0;
        for (int c = 0; c < nbuk; c += 64) {
            int i = c + lane;
            int v = (i < nbuk) ? btot[i] : 0;
            int orig = v;
            for (int d = 1; d < 64; d <<= 1) { int u = __shfl_up(v, d); if (lane >= d) v += u; }
            if (i < nbuk) lbase[i] = run + v - orig;
            run += __shfl(v, 63);
        }
        if (lane == 0) lbase[nbuk] = run;
    }
    if (t < 256) h[t] = 0;
    __syncthreads();
    int e0 = lbase[b], e1 = lbase[b + 1];
    for (int i = e0 + t; i < e1; i += 512) atomicAdd(&h[coarse[i] >> 24], 1);
    __syncthreads();
    int v = (t < 256) ? h[t] : 0;
    if (t < 256) s[t] = v;
    __syncthreads();
    for (int st = 1; st < 256; st <<= 1) {
        int add = (t < 256 && t >= st) ? s[t - st] : 0;
        __syncthreads();
        if (t < 256) s[t] += add;
        __syncthreads();
    }
    if (t < 256) {
        int excl = s[t] - v;
        int node = b * 256 + t;
        if (node < n) {
            row_ptr[node] = e0 + excl;
            dis[node] = rsqrtf((float)v + 1.0f);
        }
        cur[t] = e0 + excl;
    }
    __syncthreads();
    for (int i = e0 + t; i < e1; i += 512) {
        unsigned int pk = coarse[i];
        int p = atomicAdd(&cur[pk >> 24], 1);
        col[p] = (int)(pk & 0x00FFFFFFu);
    }
    if (b == nbuk - 1 && t == 0) row_ptr[n] = e;
}

// ---------------- MFMA GEMM (layer 2): C[r] = dis[r] * (A[r] @ W); A bf16; WTg pre-converted ----------------
__global__ __launch_bounds__(256) void gemm_mfma_k(const unsigned short* __restrict__ A, const unsigned short* __restrict__ WTg,
                                                   const float* __restrict__ dis, unsigned short* __restrict__ C,
                                                   int nrows) {
    __shared__ __align__(16) unsigned short WT[128 * 136];
    int t = threadIdx.x;
#pragma unroll
    for (int i = t; i < 2048; i += 256) {
        int nn = i >> 4, c = i & 15;
        *(u32x4*)&WT[nn * 136 + c * 8] = *(const u32x4*)&WTg[nn * 128 + c * 8];
    }
    __syncthreads();
    int wave = t >> 6, lane = t & 63;
    int lm = lane & 15, lg = lane >> 4;
    for (int m0 = blockIdx.x * 64; m0 < nrows; m0 += gridDim.x * 64) {
        int R = m0 + wave * 16;
        int arow = R + lm;
        if (arow >= nrows) arow = nrows - 1;
        f32x4 acc[8];
#pragma unroll
        for (int q = 0; q < 8; q++) acc[q] = (f32x4){0.f, 0.f, 0.f, 0.f};
#pragma unroll
        for (int kk = 0; kk < 4; kk++) {
            const u32x4* ap = (const u32x4*)(A + (size_t)arow * 128);
            bf16x8 af = __builtin_bit_cast(bf16x8, ap[kk * 4 + lg]);
#pragma unroll
            for (int q = 0; q < 8; q++) {
                const u32x4* bp = (const u32x4*)(WT + (q * 16 + lm) * 136 + kk * 32 + lg * 8);
                bf16x8 bfr = __builtin_bit_cast(bf16x8, *bp);
                acc[q] = __builtin_amdgcn_mfma_f32_16x16x32_bf16(af, bfr, acc[q], 0, 0, 0);
            }
        }
        float dsc[4];
#pragma unroll
        for (int i2 = 0; i2 < 4; i2++) {
            int r = R + lg * 4 + i2;
            dsc[i2] = (r < nrows) ? dis[r] : 0.f;
        }
#pragma unroll
        for (int i2 = 0; i2 < 4; i2++) {
            int r = R + lg * 4 + i2;
            if (r < nrows) {
                unsigned short* cp = C + (size_t)r * 128 + lm;
#pragma unroll
                for (int q = 0; q < 8; q++) cp[q * 16] = f2bf(acc[q][i2] * dsc[i2]);
            }
        }
    }
}

// ---------------- aggregation ----------------
// EDGE_DIS=true  (layer1, h=T unscaled): out = relu(b + dis[n]*(dis[n]*T[n] + sum dis[c]*T[c]))
// EDGE_DIS=false (layer2, h pre-scaled): out = relu(b + dis[n]*(h[n] + sum h[c]))
template <bool EDGE_DIS>
__global__ __launch_bounds__(256, 8) void agg_k(const unsigned short* __restrict__ h, unsigned short* __restrict__ out,
                                                const int* __restrict__ row_ptr, const int* __restrict__ col,
                                                const float* __restrict__ dis, const float* __restrict__ bias, int n) {
    int wid  = (blockIdx.x * 256 + threadIdx.x) >> 6;
    int lane = threadIdx.x & 63;
    if (wid >= n) return;
    int g = lane >> 4;                 // edge stream 0..3
    int s = lane & 15;                 // 16B chunk within 256B row
    const char* hb = (const char*)h;
    unsigned int soff = (unsigned int)(s << 4);
    float dn = dis[wid];
    float acc0 = 0.f, acc1 = 0.f, acc2 = 0.f, acc3 = 0.f;
    float acc4 = 0.f, acc5 = 0.f, acc6 = 0.f, acc7 = 0.f;
#define ACCUMW(v, w)                                                                                  \
    acc0 += (w) * __uint_as_float((v)[0] << 16); acc1 += (w) * __uint_as_float((v)[0] & 0xffff0000u); \
    acc2 += (w) * __uint_as_float((v)[1] << 16); acc3 += (w) * __uint_as_float((v)[1] & 0xffff0000u); \
    acc4 += (w) * __uint_as_float((v)[2] << 16); acc5 += (w) * __uint_as_float((v)[2] & 0xffff0000u); \
    acc6 += (w) * __uint_as_float((v)[3] << 16); acc7 += (w) * __uint_as_float((v)[3] & 0xffff0000u);
    if (g == 0) {   // self-loop row
        u32x4 v = *(const u32x4*)(hb + (((unsigned int)wid << 8) + soff));
        float w = EDGE_DIS ? dn : 1.0f;
        ACCUMW(v, w)
    }
    int e = row_ptr[wid] + g, e1 = row_ptr[wid + 1];
    for (; e + 12 < e1; e += 16) {
        int c0 = col[e], c1 = col[e + 4], c2 = col[e + 8], c3 = col[e + 12];
        float w0 = 1.f, w1 = 1.f, w2 = 1.f, w3 = 1.f;
        if constexpr (EDGE_DIS) { w0 = dis[c0]; w1 = dis[c1]; w2 = dis[c2]; w3 = dis[c3]; }
        u32x4 v0 = *(const u32x4*)(hb + (((unsigned int)c0 << 8) + soff));
        u32x4 v1 = *(const u32x4*)(hb + (((unsigned int)c1 << 8) + soff));
        u32x4 v2 = *(const u32x4*)(hb + (((unsigned int)c2 << 8) + soff));
        u32x4 v3 = *(const u32x4*)(hb + (((unsigned int)c3 << 8) + soff));
        ACCUMW(v0, w0)
        ACCUMW(v1, w1)
        ACCUMW(v2, w2)
        ACCUMW(v3, w3)
    }
    for (; e < e1; e += 4) {
        int c = col[e];
        float w = 1.f;
        if constexpr (EDGE_DIS) w = dis[c];
        u32x4 v = *(const u32x4*)(hb + (((unsigned int)c << 8) + soff));
        ACCUMW(v, w)
    }
#undef ACCUMW
#define RED(a) a += __shfl_xor(a, 16); a += __shfl_xor(a, 32);
    RED(acc0) RED(acc1) RED(acc2) RED(acc3) RED(acc4) RED(acc5) RED(acc6) RED(acc7)
#undef RED
    if (g == 0) {
        const float4* bp = (const float4*)bias;
        float4 ba = bp[2 * s], bb = bp[2 * s + 1];
        u32x4 r;
        r[0] = packbf2(fmaxf(ba.x + dn * acc0, 0.f), fmaxf(ba.y + dn * acc1, 0.f));
        r[1] = packbf2(fmaxf(ba.z + dn * acc2, 0.f), fmaxf(ba.w + dn * acc3, 0.f));
        r[2] = packbf2(fmaxf(bb.x + dn * acc4, 0.f), fmaxf(bb.y + dn * acc5, 0.f));
        r[3] = packbf2(fmaxf(bb.z + dn * acc6, 0.f), fmaxf(bb.w + dn * acc7, 0.f));
        *(u32x4*)((char*)out + (((unsigned int)wid << 8) + soff)) = r;
    }
}

// ---------------- fused global mean pool + classifier ----------------
__global__ __launch_bounds__(128) void pool_logits_k(const unsigned short* __restrict__ h, const int* __restrict__ batch,
                                                     const float* __restrict__ Wc, const float* __restrict__ bc,
                                                     float* __restrict__ logits, float* __restrict__ pooled,
                                                     int n, int nc) {
    __shared__ float pl[128];
    int g = blockIdx.x;
    int j = threadIdx.x;
    int lo = 0, hi = n;
    while (lo < hi) { int mid = (lo + hi) >> 1; if (batch[mid] < g) lo = mid + 1; else hi = mid; }
    int start = lo;
    hi = n;
    while (lo < hi) { int mid = (lo + hi) >> 1; if (batch[mid] < g + 1) lo = mid + 1; else hi = mid; }
    int end = lo;
    float acc = 0.f;
    for (int r = start; r < end; r++) acc += bf2f(h[(size_t)r * 128 + j]);
    float pv = acc / fmaxf((float)(end - start), 1.0f);
    pooled[(size_t)g * 128 + j] = pv;
    pl[j] = pv;
    __syncthreads();
    if (j < nc) {
        float a = bc[j];
#pragma unroll 8
        for (int k = 0; k < 128; k++) a += pl[k] * Wc[k * nc + j];
        logits[(size_t)g * nc + j] = a;
    }
}

extern "C" void kernel_launch(void* const* d_in, const int* in_sizes, int n_in,
                              void* d_out, int out_size, void* d_ws, size_t ws_size,
                              hipStream_t stream) {
    const float* x     = (const float*)d_in[0];
    const int*   ei    = (const int*)d_in[1];
    const int*   batch = (const int*)d_in[2];
    const float* W1    = (const float*)d_in[3];
    const float* b1    = (const float*)d_in[4];
    const float* W2    = (const float*)d_in[5];
    const float* b2    = (const float*)d_in[6];
    const float* Wc    = (const float*)d_in[7];
    const float* bc    = (const float*)d_in[8];
    float* out = (float*)d_out;

    const int N = in_sizes[0] / 128;
    const int E = in_sizes[1] / 2;
    const int NC = 10;
    const int G = out_size / (NC + 128);

    const int* src = ei;
    const int* dst = ei + E;

    const int EB   = 8192;
    const int NBLK = (E + EB - 1) / EB;
    const int NBUK = (N + 255) / 256;

    // workspace carve (256B aligned)
    char* wbase = (char*)d_ws;
    size_t off = 0;
    auto alloc = [&](size_t bytes) -> void* {
        void* p = wbase + off;
        off = (off + bytes + 255) & ~(size_t)255;
        return p;
    };
    float* dis     = (float*)alloc((size_t)N * 4);
    int*   row_ptr = (int*)alloc((size_t)(N + 1) * 4);
    int*   hist    = (int*)alloc((size_t)NBUK * NBLK * 4);
    int*   btot    = (int*)alloc((size_t)NBUK * 4);
    unsigned int* coarse = (unsigned int*)alloc((size_t)E * 4);
    int*   col     = (int*)alloc((size_t)E * 4);
    unsigned short* wt1 = (unsigned short*)alloc((size_t)128 * 128 * 2);
    unsigned short* wt2 = (unsigned short*)alloc((size_t)128 * 128 * 2);
    unsigned short* bufT = (unsigned short*)alloc((size_t)N * 128 * 2);
    unsigned short* bufH = (unsigned short*)alloc((size_t)N * 128 * 2);

    prep_k<<<64, 256, 0, stream>>>(W1, W2, wt1, wt2);

    // fused: hist + gemm1 (unscaled T = x@W1, copy-staged from wt1)
    const int G1 = 782;
    build1_k<<<NBLK + G1, 256, 0, stream>>>(dst, hist, wt1, x, bufT, N, E, NBUK, NBLK, EB, G1);
    scanA_k<<<(NBUK * 64 + 255) / 256, 256, 0, stream>>>(hist, btot, NBUK, NBLK);
    scatter_k<<<NBLK, 512, 0, stream>>>(src, dst, hist, btot, coarse, E, NBUK, NBLK, EB);
    bucket_k<<<NBUK, 512, 0, stream>>>(coarse, btot, dis, row_ptr, col, N, NBUK, E);

    agg_k<true><<<(N + 3) / 4, 256, 0, stream>>>(bufT, bufH, row_ptr, col, dis, b1, N);
    gemm_mfma_k<<<(N + 63) / 64, 256, 0, stream>>>(bufH, wt2, dis, bufT, N);
    agg_k<false><<<(N + 3) / 4, 256, 0, stream>>>(bufT, bufH, row_ptr, col, dis, b2, N);

    float* pooled = out + (size_t)G * NC;
    pool_logits_k<<<G, 128, 0, stream>>>(bufH, batch, Wc, bc, out, pooled, N, NC);
}